// Round 1
// baseline (861.568 us; speedup 1.0000x reference)
//
#include <hip/hip_runtime.h>
#include <math.h>

typedef __bf16 bf16_t;
typedef __bf16 bf16x8 __attribute__((ext_vector_type(8)));
typedef float f32x4 __attribute__((ext_vector_type(4)));

#define DIM 768
#define NE 4
#define NH 12
#define HD 64
#define MLP_HID 3072
#define FC1_OUT 5376
#define FC2_IN 3840
#define FC2_OUT 1536
#define CAP 512
#define BN 8192            // B*N tokens
#define LDS_STRIDE 40      // bf16 elems per LDS tile row (32 + 8 pad; 80B = 16B aligned, 8 bank groups)

// ---------------- weight cast fp32 -> bf16 ----------------
__global__ __launch_bounds__(256) void cast_w_kernel(const float* __restrict__ w1,
                                                     const float* __restrict__ w2,
                                                     bf16_t* __restrict__ w1b,
                                                     bf16_t* __restrict__ w2b) {
  const int N1 = FC1_OUT * DIM;          // 4128768
  const int N2 = FC2_OUT * FC2_IN;       // 5898240
  for (int i = blockIdx.x * 256 + threadIdx.x; i < N1 + N2; i += gridDim.x * 256) {
    if (i < N1) w1b[i] = (bf16_t)w1[i];
    else        w2b[i - N1] = (bf16_t)w2[i - N1];
  }
}

// ---------------- router: logits + softmax (fp32 exact) ----------------
__global__ __launch_bounds__(256) void router_kernel(const float* __restrict__ x,
                                                     const float* __restrict__ wr,
                                                     float* __restrict__ probs) {
  int t = blockIdx.x * 4 + (threadIdx.x >> 6);   // token b*1024+n
  int l = threadIdx.x & 63;
  const float* xr = x + (size_t)t * DIM;
  float a0 = 0.f, a1 = 0.f, a2 = 0.f, a3 = 0.f;
#pragma unroll
  for (int i = 0; i < 12; i++) {
    int d = l + i * 64;
    float xv = xr[d];
    a0 += xv * wr[d];
    a1 += xv * wr[DIM + d];
    a2 += xv * wr[2 * DIM + d];
    a3 += xv * wr[3 * DIM + d];
  }
#pragma unroll
  for (int off = 32; off > 0; off >>= 1) {
    a0 += __shfl_down(a0, off);
    a1 += __shfl_down(a1, off);
    a2 += __shfl_down(a2, off);
    a3 += __shfl_down(a3, off);
  }
  if (l == 0) {
    float m = fmaxf(fmaxf(a0, a1), fmaxf(a2, a3));
    float e0 = expf(a0 - m), e1 = expf(a1 - m), e2 = expf(a2 - m), e3 = expf(a3 - m);
    float inv = 1.0f / (e0 + e1 + e2 + e3);
    int b = t >> 10, n = t & 1023;
    probs[(b * NE + 0) * 1024 + n] = e0 * inv;
    probs[(b * NE + 1) * 1024 + n] = e1 * inv;
    probs[(b * NE + 2) * 1024 + n] = e2 * inv;
    probs[(b * NE + 3) * 1024 + n] = e3 * inv;
  }
}

// ---------------- exact top-k selection via ranking ----------------
__global__ __launch_bounds__(256) void rank_kernel(const float* __restrict__ probs,
                                                   int* __restrict__ idxr,
                                                   float* __restrict__ gate,
                                                   int* __restrict__ slot) {
  int be = blockIdx.y;                   // b*4+e, 0..31
  __shared__ float p[1024];
  for (int i = threadIdx.x; i < 1024; i += 256) p[i] = probs[be * 1024 + i];
  __syncthreads();
  int n = blockIdx.x * 256 + threadIdx.x;
  float pn = p[n];
  int rank = 0;
  for (int j = 0; j < 1024; j++) {
    float pj = p[j];
    rank += (pj > pn) || (pj == pn && j < n);
  }
  if (rank < CAP) {
    idxr[be * CAP + rank] = n;
    gate[be * CAP + rank] = pn;
    slot[be * 1024 + n] = rank;
  } else {
    slot[be * 1024 + n] = -1;
  }
}

// ---------------- LayerNorm -> bf16 ----------------
__global__ __launch_bounds__(256) void ln_kernel(const float* __restrict__ x,
                                                 const float* __restrict__ gamma,
                                                 const float* __restrict__ beta,
                                                 bf16_t* __restrict__ yb) {
  int t = blockIdx.x * 4 + (threadIdx.x >> 6);
  int l = threadIdx.x & 63;
  const float* xr = x + (size_t)t * DIM;
  float v[12];
  float s = 0.f, sq = 0.f;
#pragma unroll
  for (int i = 0; i < 12; i++) {
    v[i] = xr[l + i * 64];
    s += v[i];
    sq += v[i] * v[i];
  }
#pragma unroll
  for (int off = 1; off < 64; off <<= 1) {
    s += __shfl_xor(s, off);
    sq += __shfl_xor(sq, off);
  }
  float mean = s * (1.0f / DIM);
  float var = sq * (1.0f / DIM) - mean * mean;
  float rs = rsqrtf(var + 1e-6f);
#pragma unroll
  for (int i = 0; i < 12; i++) {
    int d = l + i * 64;
    yb[(size_t)t * DIM + d] = (bf16_t)((v[i] - mean) * rs * gamma[d] + beta[d]);
  }
}

// ---------------- FC1: per (b): C[e][512][5376] = gather(y)[512,K=m(e)] @ w1^T + b1 ----------------
__global__ __launch_bounds__(256) void fc1_kernel(const bf16_t* __restrict__ yb,
                                                  const bf16_t* __restrict__ w1b,
                                                  const float* __restrict__ b1,
                                                  const int* __restrict__ idxr,
                                                  bf16_t* __restrict__ h_g,
                                                  int b) {
  const int e = blockIdx.z;
  const int mt = blockIdx.y;     // 0..3
  const int nt = blockIdx.x;     // 0..41
  const int K = 96 << e;
  const int tid = threadIdx.x;
  const int w = tid >> 6, l = tid & 63;
  const int lq = l >> 4, lr = l & 15;

  __shared__ bf16_t lA[128 * LDS_STRIDE];
  __shared__ bf16_t lB[128 * LDS_STRIDE];
  __shared__ int toks[128];

  if (tid < 128) toks[tid] = idxr[(b * NE + e) * CAP + mt * 128 + tid];
  __syncthreads();

  f32x4 acc[4][4] = {};
  const int mwave = (w & 1) * 64, nwave = (w >> 1) * 64;

  for (int k0 = 0; k0 < K; k0 += 32) {
#pragma unroll
    for (int i = 0; i < 2; i++) {
      int chunk = i * 256 + tid;
      int row = chunk >> 2, c4 = chunk & 3;
      float4 va = *(const float4*)(yb + ((size_t)(b * 1024 + toks[row])) * DIM + k0 + c4 * 8);
      *(float4*)(lA + row * LDS_STRIDE + c4 * 8) = va;
      float4 vb = *(const float4*)(w1b + (size_t)(nt * 128 + row) * DIM + k0 + c4 * 8);
      *(float4*)(lB + row * LDS_STRIDE + c4 * 8) = vb;
    }
    __syncthreads();
    bf16x8 af[4], bfr[4];
#pragma unroll
    for (int mi = 0; mi < 4; mi++)
      af[mi] = *(const bf16x8*)(lA + (mwave + mi * 16 + lr) * LDS_STRIDE + lq * 8);
#pragma unroll
    for (int ni = 0; ni < 4; ni++)
      bfr[ni] = *(const bf16x8*)(lB + (nwave + ni * 16 + lr) * LDS_STRIDE + lq * 8);
#pragma unroll
    for (int mi = 0; mi < 4; mi++)
#pragma unroll
      for (int ni = 0; ni < 4; ni++)
        acc[mi][ni] = __builtin_amdgcn_mfma_f32_16x16x32_bf16(af[mi], bfr[ni], acc[mi][ni], 0, 0, 0);
    __syncthreads();
  }

#pragma unroll
  for (int mi = 0; mi < 4; mi++) {
    int row0 = mt * 128 + mwave + mi * 16 + lq * 4;
#pragma unroll
    for (int ni = 0; ni < 4; ni++) {
      int col = nt * 128 + nwave + ni * 16 + lr;
      float bias = b1[col];
#pragma unroll
      for (int r = 0; r < 4; r++) {
        h_g[((size_t)(e * CAP + row0 + r)) * FC1_OUT + col] = (bf16_t)(acc[mi][ni][r] + bias);
      }
    }
  }
}

// ---------------- combine h back to tokens + GELU + QKV split ----------------
__global__ __launch_bounds__(256) void combine_kernel(const bf16_t* __restrict__ h_g,
                                                      const int* __restrict__ slot,
                                                      bf16_t* __restrict__ y2b,
                                                      bf16_t* __restrict__ qb,
                                                      bf16_t* __restrict__ kb,
                                                      bf16_t* __restrict__ vtb,
                                                      int b) {
  int n = blockIdx.x;
  int s0 = slot[(b * NE + 0) * 1024 + n];
  int s1 = slot[(b * NE + 1) * 1024 + n];
  int s2 = slot[(b * NE + 2) * 1024 + n];
  int s3 = slot[(b * NE + 3) * 1024 + n];
  for (int f = threadIdx.x; f < FC1_OUT; f += 256) {
    float val = 0.f;
    if (s0 >= 0) val += (float)h_g[((size_t)(0 * CAP + s0)) * FC1_OUT + f];
    if (s1 >= 0) val += (float)h_g[((size_t)(1 * CAP + s1)) * FC1_OUT + f];
    if (s2 >= 0) val += (float)h_g[((size_t)(2 * CAP + s2)) * FC1_OUT + f];
    if (s3 >= 0) val += (float)h_g[((size_t)(3 * CAP + s3)) * FC1_OUT + f];
    if (f < MLP_HID) {
      float g = 0.5f * val * (1.0f + erff(val * 0.70710678118654752f));
      y2b[((size_t)(b * 1024 + n)) * FC2_IN + f] = (bf16_t)g;
    } else {
      int part = f - MLP_HID;          // 0..2303
      int comp = part / DIM;           // 0=q 1=k 2=v
      int rem = part - comp * DIM;
      int hh = rem >> 6, d = rem & 63;
      size_t base = (size_t)(b * NH + hh);
      if (comp == 0)      qb[(base * 1024 + n) * HD + d] = (bf16_t)val;
      else if (comp == 1) kb[(base * 1024 + n) * HD + d] = (bf16_t)val;
      else                vtb[(base * HD + d) * 1024 + n] = (bf16_t)val;
    }
  }
}

// ---------------- flash attention, writes attn part of y2 ----------------
__global__ __launch_bounds__(256) void attn_kernel(const bf16_t* __restrict__ qb,
                                                   const bf16_t* __restrict__ kb,
                                                   const bf16_t* __restrict__ vtb,
                                                   bf16_t* __restrict__ y2b) {
  const int bh = blockIdx.y;    // b*12+h
  const int qt = blockIdx.x;    // 0..15
  const int tid = threadIdx.x;
  const int w = tid >> 6, l = tid & 63, lq = l >> 4, lr = l & 15;

  __shared__ bf16_t lK[64 * 72];
  __shared__ bf16_t lV[64 * 72];
  __shared__ bf16_t lP[4][16 * 72];

  const bf16_t* qbase = qb + (size_t)bh * 1024 * HD;
  const bf16_t* kbase = kb + (size_t)bh * 1024 * HD;
  const bf16_t* vbase = vtb + (size_t)bh * HD * 1024;

  bf16x8 qf[2];
  int qrow = qt * 64 + w * 16 + lr;
#pragma unroll
  for (int s = 0; s < 2; s++)
    qf[s] = *(const bf16x8*)(qbase + (size_t)qrow * HD + s * 32 + lq * 8);

  f32x4 oacc[4] = {};
  float mrow[4], lrow[4];
#pragma unroll
  for (int r = 0; r < 4; r++) { mrow[r] = -1e30f; lrow[r] = 0.f; }

  for (int kt = 0; kt < 16; kt++) {
#pragma unroll
    for (int i = 0; i < 2; i++) {
      int chunk = i * 256 + tid;
      int row = chunk >> 3, c = chunk & 7;
      *(float4*)(lK + row * 72 + c * 8) =
          *(const float4*)(kbase + (size_t)(kt * 64 + row) * HD + c * 8);
      *(float4*)(lV + row * 72 + c * 8) =
          *(const float4*)(vbase + (size_t)row * 1024 + kt * 64 + c * 8);
    }
    __syncthreads();

    f32x4 sacc[4] = {};
#pragma unroll
    for (int kbq = 0; kbq < 4; kbq++)
#pragma unroll
      for (int s = 0; s < 2; s++) {
        bf16x8 kf = *(const bf16x8*)(lK + (kbq * 16 + lr) * 72 + s * 32 + lq * 8);
        sacc[kbq] = __builtin_amdgcn_mfma_f32_16x16x32_bf16(qf[s], kf, sacc[kbq], 0, 0, 0);
      }

    float sv[4][4];
    float tmax[4] = {-1e30f, -1e30f, -1e30f, -1e30f};
#pragma unroll
    for (int kbq = 0; kbq < 4; kbq++)
#pragma unroll
      for (int r = 0; r < 4; r++) {
        sv[kbq][r] = sacc[kbq][r] * 0.125f;
        tmax[r] = fmaxf(tmax[r], sv[kbq][r]);
      }
#pragma unroll
    for (int off = 1; off < 16; off <<= 1)
#pragma unroll
      for (int r = 0; r < 4; r++) tmax[r] = fmaxf(tmax[r], __shfl_xor(tmax[r], off));

    float alpha[4], psum[4] = {0.f, 0.f, 0.f, 0.f};
#pragma unroll
    for (int r = 0; r < 4; r++) {
      float mnew = fmaxf(mrow[r], tmax[r]);
      alpha[r] = expf(mrow[r] - mnew);
      mrow[r] = mnew;
    }
    float pv[4][4];
#pragma unroll
    for (int kbq = 0; kbq < 4; kbq++)
#pragma unroll
      for (int r = 0; r < 4; r++) {
        pv[kbq][r] = expf(sv[kbq][r] - mrow[r]);
        psum[r] += pv[kbq][r];
      }
#pragma unroll
    for (int off = 1; off < 16; off <<= 1)
#pragma unroll
      for (int r = 0; r < 4; r++) psum[r] += __shfl_xor(psum[r], off);
#pragma unroll
    for (int r = 0; r < 4; r++) lrow[r] = lrow[r] * alpha[r] + psum[r];
#pragma unroll
    for (int nb = 0; nb < 4; nb++)
#pragma unroll
      for (int r = 0; r < 4; r++) oacc[nb][r] *= alpha[r];

    // P: C-layout -> LDS -> A-layout
#pragma unroll
    for (int kbq = 0; kbq < 4; kbq++)
#pragma unroll
      for (int r = 0; r < 4; r++)
        lP[w][(lq * 4 + r) * 72 + kbq * 16 + lr] = (bf16_t)pv[kbq][r];
    __syncthreads();

    bf16x8 pf[2];
#pragma unroll
    for (int s = 0; s < 2; s++)
      pf[s] = *(const bf16x8*)(&lP[w][lr * 72 + s * 32 + lq * 8]);

#pragma unroll
    for (int nb = 0; nb < 4; nb++)
#pragma unroll
      for (int s = 0; s < 2; s++) {
        bf16x8 vf = *(const bf16x8*)(lV + (nb * 16 + lr) * 72 + s * 32 + lq * 8);
        oacc[nb] = __builtin_amdgcn_mfma_f32_16x16x32_bf16(pf[s], vf, oacc[nb], 0, 0, 0);
      }
    __syncthreads();
  }

  int b = bh / NH, hh = bh % NH;
#pragma unroll
  for (int nb = 0; nb < 4; nb++)
#pragma unroll
    for (int r = 0; r < 4; r++) {
      float v = oacc[nb][r] / lrow[r];
      int tok = qt * 64 + w * 16 + lq * 4 + r;
      y2b[((size_t)(b * 1024 + tok)) * FC2_IN + MLP_HID + hh * HD + nb * 16 + lr] = (bf16_t)v;
    }
}

// ---------------- FC2: o[b][e][512][1536 masked] = gather(y2)[512,3840] @ w2^T + b2 ----------------
__global__ __launch_bounds__(256) void fc2_kernel(const bf16_t* __restrict__ y2b,
                                                  const bf16_t* __restrict__ w2b,
                                                  const float* __restrict__ b2,
                                                  const int* __restrict__ idxr,
                                                  bf16_t* __restrict__ o_g) {
  const int b = blockIdx.z;
  const int mt = blockIdx.y;
  const int ct = blockIdx.x;   // 0..23
  int e, t;
  if (ct < 2)       { e = 0; t = ct; }
  else if (ct < 6)  { e = 1; t = ct - 2; }
  else if (ct < 12) { e = 2; t = ct - 6; }
  else              { e = 3; t = ct - 12; }
  const int per_half = (e == 0) ? 1 : (e == 1) ? 2 : (e == 2) ? 3 : 6;
  const int m_e = 96 << e;
  const int half = t / per_half, within = t - half * per_half;
  const int colbase = half * DIM + within * 128;
  const int colvalid = min(128, m_e - within * 128);

  const int tid = threadIdx.x;
  const int w = tid >> 6, l = tid & 63;
  const int lq = l >> 4, lr = l & 15;

  __shared__ bf16_t lA[128 * LDS_STRIDE];
  __shared__ bf16_t lB[128 * LDS_STRIDE];
  __shared__ int toks[128];

  if (tid < 128) toks[tid] = idxr[(b * NE + e) * CAP + mt * 128 + tid];
  __syncthreads();

  f32x4 acc[4][4] = {};
  const int mwave = (w & 1) * 64, nwave = (w >> 1) * 64;

  for (int k0 = 0; k0 < FC2_IN; k0 += 32) {
#pragma unroll
    for (int i = 0; i < 2; i++) {
      int chunk = i * 256 + tid;
      int row = chunk >> 2, c4 = chunk & 3;
      float4 va = *(const float4*)(y2b + ((size_t)(b * 1024 + toks[row])) * FC2_IN + k0 + c4 * 8);
      *(float4*)(lA + row * LDS_STRIDE + c4 * 8) = va;
      float4 vb = *(const float4*)(w2b + (size_t)(colbase + row) * FC2_IN + k0 + c4 * 8);
      *(float4*)(lB + row * LDS_STRIDE + c4 * 8) = vb;
    }
    __syncthreads();
    bf16x8 af[4], bfr[4];
#pragma unroll
    for (int mi = 0; mi < 4; mi++)
      af[mi] = *(const bf16x8*)(lA + (mwave + mi * 16 + lr) * LDS_STRIDE + lq * 8);
#pragma unroll
    for (int ni = 0; ni < 4; ni++)
      bfr[ni] = *(const bf16x8*)(lB + (nwave + ni * 16 + lr) * LDS_STRIDE + lq * 8);
#pragma unroll
    for (int mi = 0; mi < 4; mi++)
#pragma unroll
      for (int ni = 0; ni < 4; ni++)
        acc[mi][ni] = __builtin_amdgcn_mfma_f32_16x16x32_bf16(af[mi], bfr[ni], acc[mi][ni], 0, 0, 0);
    __syncthreads();
  }

#pragma unroll
  for (int mi = 0; mi < 4; mi++) {
    int row0 = mt * 128 + mwave + mi * 16 + lq * 4;
#pragma unroll
    for (int ni = 0; ni < 4; ni++) {
      int cl = nwave + ni * 16 + lr;
      if (cl < colvalid) {
        int col = colbase + cl;
        float bias = b2[col];
#pragma unroll
        for (int r = 0; r < 4; r++) {
          o_g[((size_t)((b * NE + e) * CAP + row0 + r)) * FC2_OUT + col] =
              (bf16_t)(acc[mi][ni][r] + bias);
        }
      }
    }
  }
}

// ---------------- final: out = x + gate-weighted masked scatter of o ----------------
__global__ __launch_bounds__(256) void final_kernel(const float* __restrict__ x,
                                                    const bf16_t* __restrict__ o_g,
                                                    const float* __restrict__ gate,
                                                    const int* __restrict__ slot,
                                                    float* __restrict__ out) {
  int t = blockIdx.x;            // b*1024+n
  int b = t >> 10, n = t & 1023;
  int s[NE]; float g[NE];
#pragma unroll
  for (int e = 0; e < NE; e++) {
    s[e] = slot[(b * NE + e) * 1024 + n];
    g[e] = (s[e] >= 0) ? gate[(b * NE + e) * CAP + s[e]] : 0.f;
  }
  for (int d = threadIdx.x; d < DIM; d += 256) {
    float acc = x[(size_t)t * DIM + d];
#pragma unroll
    for (int e = 0; e < NE; e++) {
      int m_e = 96 << e;
      if (s[e] >= 0 && d < m_e) {
        size_t base = ((size_t)((b * NE + e) * CAP + s[e])) * FC2_OUT;
        acc += g[e] * ((float)o_g[base + d] + (float)o_g[base + DIM + d]);
      }
    }
    out[(size_t)t * DIM + d] = acc;
  }
}

extern "C" void kernel_launch(void* const* d_in, const int* in_sizes, int n_in,
                              void* d_out, int out_size, void* d_ws, size_t ws_size,
                              hipStream_t stream) {
  const float* x     = (const float*)d_in[0];
  const float* wr    = (const float*)d_in[1];
  const float* gamma = (const float*)d_in[2];
  const float* beta  = (const float*)d_in[3];
  const float* w1    = (const float*)d_in[4];
  const float* b1    = (const float*)d_in[5];
  const float* w2    = (const float*)d_in[6];
  const float* b2    = (const float*)d_in[7];
  float* out = (float*)d_out;

  // workspace arena (bytes); total 155713536 (~149 MB)
  char* ws = (char*)d_ws;
  float*  probs = (float*)(ws + 0);            // 131072
  int*    idxr  = (int*)  (ws + 131072);       // 65536
  float*  gate  = (float*)(ws + 196608);       // 65536
  int*    slot  = (int*)  (ws + 262144);       // 131072
  bf16_t* w1b   = (bf16_t*)(ws + 393216);      // 8257536
  bf16_t* w2b   = (bf16_t*)(ws + 8650752);     // 11796480
  bf16_t* yb    = (bf16_t*)(ws + 20447232);    // 12582912
  bf16_t* y2b   = (bf16_t*)(ws + 33030144);    // 62914560
  bf16_t* h_g   = (bf16_t*)(ws + 95944704);    // 22020096 (per-batch, reused)
  bf16_t* qb    = (bf16_t*)(ws + 117964800);   // 12582912
  bf16_t* kb    = (bf16_t*)(ws + 130547712);   // 12582912
  bf16_t* vtb   = (bf16_t*)(ws + 143130624);   // 12582912
  bf16_t* o_g   = (bf16_t*)(ws + 95944704);    // 50331648, aliases dead h_g/qkv

  cast_w_kernel<<<2048, 256, 0, stream>>>(w1, w2, w1b, w2b);
  router_kernel<<<2048, 256, 0, stream>>>(x, wr, probs);
  rank_kernel<<<dim3(4, 32), 256, 0, stream>>>(probs, idxr, gate, slot);
  ln_kernel<<<2048, 256, 0, stream>>>(x, gamma, beta, yb);
  for (int b = 0; b < 8; b++) {
    fc1_kernel<<<dim3(42, 4, 4), 256, 0, stream>>>(yb, w1b, b1, idxr, h_g, b);
    combine_kernel<<<1024, 256, 0, stream>>>(h_g, slot, y2b, qb, kb, vtb, b);
  }
  attn_kernel<<<dim3(16, 96), 256, 0, stream>>>(qb, kb, vtb, y2b);
  fc2_kernel<<<dim3(24, 4, 8), 256, 0, stream>>>(y2b, w2b, b2, idxr, o_g);
  final_kernel<<<8192, 256, 0, stream>>>(x, o_g, gate, slot, out);
}

// Round 2
// 632.854 us; speedup vs baseline: 1.3614x; 1.3614x over previous
//
#include <hip/hip_runtime.h>
#include <math.h>

typedef __bf16 bf16_t;
typedef __bf16 bf16x8 __attribute__((ext_vector_type(8)));
typedef float f32x4 __attribute__((ext_vector_type(4)));

#define DIM 768
#define NE 4
#define NH 12
#define HD 64
#define MLP_HID 3072
#define FC1_OUT 5376
#define FC2_IN 3840
#define CAP 512
#define LDS_STRIDE 40      // bf16 elems per LDS tile row (32 + 8 pad)

// ---------------- weight cast fp32 -> bf16 ----------------
__global__ __launch_bounds__(256) void cast_w_kernel(const float* __restrict__ w1,
                                                     const float* __restrict__ w2,
                                                     bf16_t* __restrict__ w1b,
                                                     bf16_t* __restrict__ w2b) {
  const int N1 = FC1_OUT * DIM;
  const int N2 = 1536 * FC2_IN;
  for (int i = blockIdx.x * 256 + threadIdx.x; i < N1 + N2; i += gridDim.x * 256) {
    if (i < N1) w1b[i] = (bf16_t)w1[i];
    else        w2b[i - N1] = (bf16_t)w2[i - N1];
  }
}

// ---------------- router: logits + softmax (fp32 exact) ----------------
__global__ __launch_bounds__(256) void router_kernel(const float* __restrict__ x,
                                                     const float* __restrict__ wr,
                                                     float* __restrict__ probs) {
  int t = blockIdx.x * 4 + (threadIdx.x >> 6);
  int l = threadIdx.x & 63;
  const float* xr = x + (size_t)t * DIM;
  float a0 = 0.f, a1 = 0.f, a2 = 0.f, a3 = 0.f;
#pragma unroll
  for (int i = 0; i < 12; i++) {
    int d = l + i * 64;
    float xv = xr[d];
    a0 += xv * wr[d];
    a1 += xv * wr[DIM + d];
    a2 += xv * wr[2 * DIM + d];
    a3 += xv * wr[3 * DIM + d];
  }
#pragma unroll
  for (int off = 32; off > 0; off >>= 1) {
    a0 += __shfl_down(a0, off);
    a1 += __shfl_down(a1, off);
    a2 += __shfl_down(a2, off);
    a3 += __shfl_down(a3, off);
  }
  if (l == 0) {
    float m = fmaxf(fmaxf(a0, a1), fmaxf(a2, a3));
    float e0 = expf(a0 - m), e1 = expf(a1 - m), e2 = expf(a2 - m), e3 = expf(a3 - m);
    float inv = 1.0f / (e0 + e1 + e2 + e3);
    int b = t >> 10, n = t & 1023;
    probs[(b * NE + 0) * 1024 + n] = e0 * inv;
    probs[(b * NE + 1) * 1024 + n] = e1 * inv;
    probs[(b * NE + 2) * 1024 + n] = e2 * inv;
    probs[(b * NE + 3) * 1024 + n] = e3 * inv;
  }
}

// ---------------- exact top-k membership via ranking ----------------
__global__ __launch_bounds__(256) void rank_kernel(const float* __restrict__ probs,
                                                   float* __restrict__ gate_tok) {
  int be = blockIdx.y;                   // b*4+e
  __shared__ float p[1024];
  for (int i = threadIdx.x; i < 1024; i += 256) p[i] = probs[be * 1024 + i];
  __syncthreads();
  int n = blockIdx.x * 256 + threadIdx.x;
  float pn = p[n];
  int rank = 0;
  for (int j = 0; j < 1024; j++) {
    float pj = p[j];
    rank += (pj > pn) || (pj == pn && j < n);
  }
  int b = be >> 2, e = be & 3;
  gate_tok[(size_t)((b << 10) + n) * 4 + e] = (rank < CAP) ? pn : 0.0f;
}

// ---------------- LayerNorm + segment-count scaling -> bf16; emit cnt + gate suffix sums ----------------
__global__ __launch_bounds__(256) void ln_kernel(const float* __restrict__ x,
                                                 const float* __restrict__ gamma,
                                                 const float* __restrict__ beta,
                                                 const float* __restrict__ gate_tok,
                                                 bf16_t* __restrict__ ytil,
                                                 float* __restrict__ cntf,
                                                 float* __restrict__ g4) {
  int t = blockIdx.x * 4 + (threadIdx.x >> 6);
  int l = threadIdx.x & 63;
  float4 gg = ((const float4*)gate_tok)[t];
  float s0 = (gg.x > 0.f) ? 1.f : 0.f;
  float s1 = (gg.y > 0.f) ? 1.f : 0.f;
  float s2 = (gg.z > 0.f) ? 1.f : 0.f;
  float s3 = (gg.w > 0.f) ? 1.f : 0.f;
  float c3 = s3, c2 = c3 + s2, c1 = c2 + s1, c0 = c1 + s0;
  if (l == 0) {
    cntf[t] = c0;
    float4 G;
    G.x = gg.x + gg.y + gg.z + gg.w;
    G.y = gg.y + gg.z + gg.w;
    G.z = gg.z + gg.w;
    G.w = gg.w;
    ((float4*)g4)[t] = G;
  }
  const float* xr = x + (size_t)t * DIM;
  float v[12];
  float s = 0.f, sq = 0.f;
#pragma unroll
  for (int i = 0; i < 12; i++) {
    v[i] = xr[l + i * 64];
    s += v[i];
    sq += v[i] * v[i];
  }
#pragma unroll
  for (int off = 1; off < 64; off <<= 1) {
    s += __shfl_xor(s, off);
    sq += __shfl_xor(sq, off);
  }
  float mean = s * (1.0f / DIM);
  float var = sq * (1.0f / DIM) - mean * mean;
  float rs = rsqrtf(var + 1e-6f);
#pragma unroll
  for (int i = 0; i < 12; i++) {
    int d = l + i * 64;
    float cf = (d < 96) ? c0 : (d < 192) ? c1 : (d < 384) ? c2 : c3;
    ytil[(size_t)t * DIM + d] = (bf16_t)(((v[i] - mean) * rs * gamma[d] + beta[d]) * cf);
  }
}

// ---------------- FC1 dense: [8192,5376] = ytil @ w1^T + cnt*b1; epilogue gelu / qkv split ----------------
__global__ __launch_bounds__(256) void fc1_kernel(const bf16_t* __restrict__ ytil,
                                                  const bf16_t* __restrict__ w1b,
                                                  const float* __restrict__ b1,
                                                  const float* __restrict__ cntf,
                                                  bf16_t* __restrict__ y2b,
                                                  bf16_t* __restrict__ qb,
                                                  bf16_t* __restrict__ kb,
                                                  bf16_t* __restrict__ vtb) {
  const int nt = blockIdx.x;     // 0..41
  const int mt = blockIdx.y;     // 0..63
  const int tid = threadIdx.x;
  const int w = tid >> 6, l = tid & 63;
  const int lq = l >> 4, lr = l & 15;

  __shared__ bf16_t lA[128 * LDS_STRIDE];
  __shared__ bf16_t lB[128 * LDS_STRIDE];

  f32x4 acc[4][4] = {};
  const int mwave = (w & 1) * 64, nwave = (w >> 1) * 64;
  const int arow = tid >> 2, ac4 = tid & 3;

  for (int k0 = 0; k0 < DIM; k0 += 32) {
#pragma unroll
    for (int i = 0; i < 2; i++) {
      int row = i * 64 + arow;
      *(float4*)(lA + row * LDS_STRIDE + ac4 * 8) =
          *(const float4*)(ytil + (size_t)(mt * 128 + row) * DIM + k0 + ac4 * 8);
      *(float4*)(lB + row * LDS_STRIDE + ac4 * 8) =
          *(const float4*)(w1b + (size_t)(nt * 128 + row) * DIM + k0 + ac4 * 8);
    }
    __syncthreads();
    bf16x8 af[4], bfr[4];
#pragma unroll
    for (int mi = 0; mi < 4; mi++)
      af[mi] = *(const bf16x8*)(lA + (mwave + mi * 16 + lr) * LDS_STRIDE + lq * 8);
#pragma unroll
    for (int ni = 0; ni < 4; ni++)
      bfr[ni] = *(const bf16x8*)(lB + (nwave + ni * 16 + lr) * LDS_STRIDE + lq * 8);
#pragma unroll
    for (int mi = 0; mi < 4; mi++)
#pragma unroll
      for (int ni = 0; ni < 4; ni++)
        acc[mi][ni] = __builtin_amdgcn_mfma_f32_16x16x32_bf16(af[mi], bfr[ni], acc[mi][ni], 0, 0, 0);
    __syncthreads();
  }

#pragma unroll
  for (int mi = 0; mi < 4; mi++) {
    int row0 = mt * 128 + mwave + mi * 16 + lq * 4;
    float cnt[4];
#pragma unroll
    for (int r = 0; r < 4; r++) cnt[r] = cntf[row0 + r];
#pragma unroll
    for (int ni = 0; ni < 4; ni++) {
      int col = nt * 128 + nwave + ni * 16 + lr;
      float bias = b1[col];
      if (col < MLP_HID) {
#pragma unroll
        for (int r = 0; r < 4; r++) {
          float v = acc[mi][ni][r] + cnt[r] * bias;
          float g = 0.5f * v * (1.0f + erff(v * 0.70710678118654752f));
          y2b[(size_t)(row0 + r) * FC2_IN + col] = (bf16_t)g;
        }
      } else {
        int part = col - MLP_HID;
        int comp = (part >= 1536) ? 2 : (part >= 768) ? 1 : 0;
        int rem = part - comp * 768;
        int hh = rem >> 6, d = rem & 63;
#pragma unroll
        for (int r = 0; r < 4; r++) {
          float v = acc[mi][ni][r] + cnt[r] * bias;
          int t = row0 + r;
          int b = t >> 10, n = t & 1023;
          size_t base = (size_t)(b * NH + hh);
          if (comp == 0)      qb[(base * 1024 + n) * HD + d] = (bf16_t)v;
          else if (comp == 1) kb[(base * 1024 + n) * HD + d] = (bf16_t)v;
          else                vtb[(base * HD + d) * 1024 + n] = (bf16_t)v;
        }
      }
    }
  }
}

// ---------------- flash attention, writes attn part of y2 ----------------
__global__ __launch_bounds__(256) void attn_kernel(const bf16_t* __restrict__ qb,
                                                   const bf16_t* __restrict__ kb,
                                                   const bf16_t* __restrict__ vtb,
                                                   bf16_t* __restrict__ y2b) {
  const int bh = blockIdx.y;
  const int qt = blockIdx.x;
  const int tid = threadIdx.x;
  const int w = tid >> 6, l = tid & 63, lq = l >> 4, lr = l & 15;

  __shared__ bf16_t lK[64 * 72];
  __shared__ bf16_t lV[64 * 72];
  __shared__ bf16_t lP[4][16 * 72];

  const bf16_t* qbase = qb + (size_t)bh * 1024 * HD;
  const bf16_t* kbase = kb + (size_t)bh * 1024 * HD;
  const bf16_t* vbase = vtb + (size_t)bh * HD * 1024;

  bf16x8 qf[2];
  int qrow = qt * 64 + w * 16 + lr;
#pragma unroll
  for (int s = 0; s < 2; s++)
    qf[s] = *(const bf16x8*)(qbase + (size_t)qrow * HD + s * 32 + lq * 8);

  f32x4 oacc[4] = {};
  float mrow[4], lrow[4];
#pragma unroll
  for (int r = 0; r < 4; r++) { mrow[r] = -1e30f; lrow[r] = 0.f; }

  for (int kt = 0; kt < 16; kt++) {
#pragma unroll
    for (int i = 0; i < 2; i++) {
      int chunk = i * 256 + tid;
      int row = chunk >> 3, c = chunk & 7;
      *(float4*)(lK + row * 72 + c * 8) =
          *(const float4*)(kbase + (size_t)(kt * 64 + row) * HD + c * 8);
      *(float4*)(lV + row * 72 + c * 8) =
          *(const float4*)(vbase + (size_t)row * 1024 + kt * 64 + c * 8);
    }
    __syncthreads();

    f32x4 sacc[4] = {};
#pragma unroll
    for (int kbq = 0; kbq < 4; kbq++)
#pragma unroll
      for (int s = 0; s < 2; s++) {
        bf16x8 kf = *(const bf16x8*)(lK + (kbq * 16 + lr) * 72 + s * 32 + lq * 8);
        sacc[kbq] = __builtin_amdgcn_mfma_f32_16x16x32_bf16(qf[s], kf, sacc[kbq], 0, 0, 0);
      }

    float sv[4][4];
    float tmax[4] = {-1e30f, -1e30f, -1e30f, -1e30f};
#pragma unroll
    for (int kbq = 0; kbq < 4; kbq++)
#pragma unroll
      for (int r = 0; r < 4; r++) {
        sv[kbq][r] = sacc[kbq][r] * 0.125f;
        tmax[r] = fmaxf(tmax[r], sv[kbq][r]);
      }
#pragma unroll
    for (int off = 1; off < 16; off <<= 1)
#pragma unroll
      for (int r = 0; r < 4; r++) tmax[r] = fmaxf(tmax[r], __shfl_xor(tmax[r], off));

    float alpha[4], psum[4] = {0.f, 0.f, 0.f, 0.f};
#pragma unroll
    for (int r = 0; r < 4; r++) {
      float mnew = fmaxf(mrow[r], tmax[r]);
      alpha[r] = expf(mrow[r] - mnew);
      mrow[r] = mnew;
    }
    float pv[4][4];
#pragma unroll
    for (int kbq = 0; kbq < 4; kbq++)
#pragma unroll
      for (int r = 0; r < 4; r++) {
        pv[kbq][r] = expf(sv[kbq][r] - mrow[r]);
        psum[r] += pv[kbq][r];
      }
#pragma unroll
    for (int off = 1; off < 16; off <<= 1)
#pragma unroll
      for (int r = 0; r < 4; r++) psum[r] += __shfl_xor(psum[r], off);
#pragma unroll
    for (int r = 0; r < 4; r++) lrow[r] = lrow[r] * alpha[r] + psum[r];
#pragma unroll
    for (int nb = 0; nb < 4; nb++)
#pragma unroll
      for (int r = 0; r < 4; r++) oacc[nb][r] *= alpha[r];

#pragma unroll
    for (int kbq = 0; kbq < 4; kbq++)
#pragma unroll
      for (int r = 0; r < 4; r++)
        lP[w][(lq * 4 + r) * 72 + kbq * 16 + lr] = (bf16_t)pv[kbq][r];
    __syncthreads();

    bf16x8 pf[2];
#pragma unroll
    for (int s = 0; s < 2; s++)
      pf[s] = *(const bf16x8*)(&lP[w][lr * 72 + s * 32 + lq * 8]);

#pragma unroll
    for (int nb = 0; nb < 4; nb++)
#pragma unroll
      for (int s = 0; s < 2; s++) {
        bf16x8 vf = *(const bf16x8*)(lV + (nb * 16 + lr) * 72 + s * 32 + lq * 8);
        oacc[nb] = __builtin_amdgcn_mfma_f32_16x16x32_bf16(pf[s], vf, oacc[nb], 0, 0, 0);
      }
    __syncthreads();
  }

  int b = bh / NH, hh = bh % NH;
#pragma unroll
  for (int nb = 0; nb < 4; nb++)
#pragma unroll
    for (int r = 0; r < 4; r++) {
      float v = oacc[nb][r] / lrow[r];
      int tok = qt * 64 + w * 16 + lq * 4 + r;
      y2b[((size_t)(b * 1024 + tok)) * FC2_IN + MLP_HID + hh * HD + nb * 16 + lr] = (bf16_t)v;
    }
}

// ---------------- FC2 dense fused: out = x + Sum_halves G_seg(col) * (y2 @ w2^T + b2) ----------------
__global__ __launch_bounds__(256) void fc2_kernel(const bf16_t* __restrict__ y2b,
                                                  const bf16_t* __restrict__ w2b,
                                                  const float* __restrict__ b2,
                                                  const float* __restrict__ g4,
                                                  const float* __restrict__ x,
                                                  float* __restrict__ out) {
  const int ct = blockIdx.x;   // 0..11 -> cols [ct*64, ct*64+64) in both halves
  const int mt = blockIdx.y;   // 0..63
  const int tid = threadIdx.x;
  const int w = tid >> 6, l = tid & 63;
  const int lq = l >> 4, lr = l & 15;

  __shared__ bf16_t lA[128 * LDS_STRIDE];
  __shared__ bf16_t lB[2 * 64 * LDS_STRIDE];

  f32x4 acc[2][4][2] = {};
  const int mwave = (w & 1) * 64, nwave = (w >> 1) * 32;
  const int arow = tid >> 2, ac4 = tid & 3;

  for (int k0 = 0; k0 < FC2_IN; k0 += 32) {
#pragma unroll
    for (int i = 0; i < 2; i++) {
      int row = i * 64 + arow;
      *(float4*)(lA + row * LDS_STRIDE + ac4 * 8) =
          *(const float4*)(y2b + (size_t)(mt * 128 + row) * FC2_IN + k0 + ac4 * 8);
      *(float4*)(lB + (i * 64 + arow) * LDS_STRIDE + ac4 * 8) =
          *(const float4*)(w2b + (size_t)(i * 768 + ct * 64 + arow) * FC2_IN + k0 + ac4 * 8);
    }
    __syncthreads();
    bf16x8 af[4], bfr[2][2];
#pragma unroll
    for (int mi = 0; mi < 4; mi++)
      af[mi] = *(const bf16x8*)(lA + (mwave + mi * 16 + lr) * LDS_STRIDE + lq * 8);
#pragma unroll
    for (int h = 0; h < 2; h++)
#pragma unroll
      for (int ni = 0; ni < 2; ni++)
        bfr[h][ni] = *(const bf16x8*)(lB + (h * 64 + nwave + ni * 16 + lr) * LDS_STRIDE + lq * 8);
#pragma unroll
    for (int h = 0; h < 2; h++)
#pragma unroll
      for (int mi = 0; mi < 4; mi++)
#pragma unroll
        for (int ni = 0; ni < 2; ni++)
          acc[h][mi][ni] = __builtin_amdgcn_mfma_f32_16x16x32_bf16(af[mi], bfr[h][ni], acc[h][mi][ni], 0, 0, 0);
    __syncthreads();
  }

#pragma unroll
  for (int mi = 0; mi < 4; mi++) {
    int row0 = mt * 128 + mwave + mi * 16 + lq * 4;
    float4 G[4];
#pragma unroll
    for (int r = 0; r < 4; r++) G[r] = ((const float4*)g4)[row0 + r];
#pragma unroll
    for (int ni = 0; ni < 2; ni++) {
      int col = ct * 64 + nwave + ni * 16 + lr;   // 0..767
      float b20 = b2[col], b21 = b2[768 + col];
#pragma unroll
      for (int r = 0; r < 4; r++) {
        float gw = (col < 96) ? G[r].x : (col < 192) ? G[r].y : (col < 384) ? G[r].z : G[r].w;
        float o = (acc[0][mi][ni][r] + b20) + (acc[1][mi][ni][r] + b21);
        size_t idx = (size_t)(row0 + r) * DIM + col;
        out[idx] = x[idx] + gw * o;
      }
    }
  }
}

extern "C" void kernel_launch(void* const* d_in, const int* in_sizes, int n_in,
                              void* d_out, int out_size, void* d_ws, size_t ws_size,
                              hipStream_t stream) {
  const float* x     = (const float*)d_in[0];
  const float* wr    = (const float*)d_in[1];
  const float* gamma = (const float*)d_in[2];
  const float* beta  = (const float*)d_in[3];
  const float* w1    = (const float*)d_in[4];
  const float* b1    = (const float*)d_in[5];
  const float* w2    = (const float*)d_in[6];
  const float* b2    = (const float*)d_in[7];
  float* out = (float*)d_out;

  // workspace arena (bytes)
  char* ws = (char*)d_ws;
  float*  probs    = (float*)(ws + 0);            // 131072
  float*  gate_tok = (float*)(ws + 131072);       // 131072
  float*  cntf     = (float*)(ws + 262144);       // 32768
  float*  g4       = (float*)(ws + 294912);       // 131072
  bf16_t* w1b      = (bf16_t*)(ws + 425984);      // 8257536
  bf16_t* w2b      = (bf16_t*)(ws + 8683520);     // 11796480
  bf16_t* ytil     = (bf16_t*)(ws + 20480000);    // 12582912
  bf16_t* y2b      = (bf16_t*)(ws + 33062912);    // 62914560
  bf16_t* qb       = (bf16_t*)(ws + 95977472);    // 12582912
  bf16_t* kb       = (bf16_t*)(ws + 108560384);   // 12582912
  bf16_t* vtb      = (bf16_t*)(ws + 121143296);   // 12582912
  // total 133726208 bytes

  cast_w_kernel<<<2048, 256, 0, stream>>>(w1, w2, w1b, w2b);
  router_kernel<<<2048, 256, 0, stream>>>(x, wr, probs);
  rank_kernel<<<dim3(4, 32), 256, 0, stream>>>(probs, gate_tok);
  ln_kernel<<<2048, 256, 0, stream>>>(x, gamma, beta, gate_tok, ytil, cntf, g4);
  fc1_kernel<<<dim3(42, 64), 256, 0, stream>>>(ytil, w1b, b1, cntf, y2b, qb, kb, vtb);
  attn_kernel<<<dim3(16, 96), 256, 0, stream>>>(qb, kb, vtb, y2b);
  fc2_kernel<<<dim3(12, 64), 256, 0, stream>>>(y2b, w2b, b2, g4, x, out);
}

// Round 3
// 556.293 us; speedup vs baseline: 1.5488x; 1.1376x over previous
//
#include <hip/hip_runtime.h>
#include <math.h>

typedef __bf16 bf16_t;
typedef __bf16 bf16x8 __attribute__((ext_vector_type(8)));
typedef float f32x4 __attribute__((ext_vector_type(4)));

#define DIM 768
#define NE 4
#define NH 12
#define HD 64
#define MLP_HID 3072
#define FC1_OUT 5376
#define FC2_IN 3840
#define CAP 512

__device__ __forceinline__ void async_copy16(const void* g, void* l) {
  __builtin_amdgcn_global_load_lds((const __attribute__((address_space(1))) void*)g,
                                   (__attribute__((address_space(3))) void*)l, 16, 0, 0);
}

// ---------------- weight cast fp32 -> bf16 ----------------
__global__ __launch_bounds__(256) void cast_w_kernel(const float* __restrict__ w1,
                                                     const float* __restrict__ w2,
                                                     bf16_t* __restrict__ w1b,
                                                     bf16_t* __restrict__ w2b) {
  const int N1 = FC1_OUT * DIM;
  const int N2 = 1536 * FC2_IN;
  for (int i = blockIdx.x * 256 + threadIdx.x; i < N1 + N2; i += gridDim.x * 256) {
    if (i < N1) w1b[i] = (bf16_t)w1[i];
    else        w2b[i - N1] = (bf16_t)w2[i - N1];
  }
}

// ---------------- router: logits + softmax (fp32 exact) ----------------
__global__ __launch_bounds__(256) void router_kernel(const float* __restrict__ x,
                                                     const float* __restrict__ wr,
                                                     float* __restrict__ probs) {
  int t = blockIdx.x * 4 + (threadIdx.x >> 6);
  int l = threadIdx.x & 63;
  const float* xr = x + (size_t)t * DIM;
  float a0 = 0.f, a1 = 0.f, a2 = 0.f, a3 = 0.f;
#pragma unroll
  for (int i = 0; i < 12; i++) {
    int d = l + i * 64;
    float xv = xr[d];
    a0 += xv * wr[d];
    a1 += xv * wr[DIM + d];
    a2 += xv * wr[2 * DIM + d];
    a3 += xv * wr[3 * DIM + d];
  }
#pragma unroll
  for (int off = 32; off > 0; off >>= 1) {
    a0 += __shfl_down(a0, off);
    a1 += __shfl_down(a1, off);
    a2 += __shfl_down(a2, off);
    a3 += __shfl_down(a3, off);
  }
  if (l == 0) {
    float m = fmaxf(fmaxf(a0, a1), fmaxf(a2, a3));
    float e0 = expf(a0 - m), e1 = expf(a1 - m), e2 = expf(a2 - m), e3 = expf(a3 - m);
    float inv = 1.0f / (e0 + e1 + e2 + e3);
    int b = t >> 10, n = t & 1023;
    probs[(b * NE + 0) * 1024 + n] = e0 * inv;
    probs[(b * NE + 1) * 1024 + n] = e1 * inv;
    probs[(b * NE + 2) * 1024 + n] = e2 * inv;
    probs[(b * NE + 3) * 1024 + n] = e3 * inv;
  }
}

// ---------------- exact top-k membership via ranking ----------------
__global__ __launch_bounds__(256) void rank_kernel(const float* __restrict__ probs,
                                                   float* __restrict__ gate_tok) {
  int be = blockIdx.y;
  __shared__ float p[1024];
  for (int i = threadIdx.x; i < 1024; i += 256) p[i] = probs[be * 1024 + i];
  __syncthreads();
  int n = blockIdx.x * 256 + threadIdx.x;
  float pn = p[n];
  int rank = 0;
  for (int j = 0; j < 1024; j++) {
    float pj = p[j];
    rank += (pj > pn) || (pj == pn && j < n);
  }
  int b = be >> 2, e = be & 3;
  gate_tok[(size_t)((b << 10) + n) * 4 + e] = (rank < CAP) ? pn : 0.0f;
}

// ---------------- LayerNorm + segment-count scaling -> bf16; emit gate suffix sums ----------------
__global__ __launch_bounds__(256) void ln_kernel(const float* __restrict__ x,
                                                 const float* __restrict__ gamma,
                                                 const float* __restrict__ beta,
                                                 const float* __restrict__ gate_tok,
                                                 bf16_t* __restrict__ ytil,
                                                 float* __restrict__ cntf,
                                                 float* __restrict__ g4) {
  int t = blockIdx.x * 4 + (threadIdx.x >> 6);
  int l = threadIdx.x & 63;
  float4 gg = ((const float4*)gate_tok)[t];
  float s0 = (gg.x > 0.f) ? 1.f : 0.f;
  float s1 = (gg.y > 0.f) ? 1.f : 0.f;
  float s2 = (gg.z > 0.f) ? 1.f : 0.f;
  float s3 = (gg.w > 0.f) ? 1.f : 0.f;
  float c3 = s3, c2 = c3 + s2, c1 = c2 + s1, c0 = c1 + s0;
  if (l == 0) {
    cntf[t] = c0;
    float4 G;
    G.x = gg.x + gg.y + gg.z + gg.w;
    G.y = gg.y + gg.z + gg.w;
    G.z = gg.z + gg.w;
    G.w = gg.w;
    ((float4*)g4)[t] = G;
  }
  const float* xr = x + (size_t)t * DIM;
  float v[12];
  float s = 0.f, sq = 0.f;
#pragma unroll
  for (int i = 0; i < 12; i++) {
    v[i] = xr[l + i * 64];
    s += v[i];
    sq += v[i] * v[i];
  }
#pragma unroll
  for (int off = 1; off < 64; off <<= 1) {
    s += __shfl_xor(s, off);
    sq += __shfl_xor(sq, off);
  }
  float mean = s * (1.0f / DIM);
  float var = sq * (1.0f / DIM) - mean * mean;
  float rs = rsqrtf(var + 1e-6f);
#pragma unroll
  for (int i = 0; i < 12; i++) {
    int d = l + i * 64;
    float cf = (d < 96) ? c0 : (d < 192) ? c1 : (d < 384) ? c2 : c3;
    ytil[(size_t)t * DIM + d] = (bf16_t)(((v[i] - mean) * rs * gamma[d] + beta[d]) * cf);
  }
}

// ---------------- FC1 dense: [8192,5376] = ytil @ w1^T + cnt*b1; epilogue gelu / qkv split ----------------
__global__ __launch_bounds__(256) void fc1_kernel(const bf16_t* __restrict__ ytil,
                                                  const bf16_t* __restrict__ w1b,
                                                  const float* __restrict__ b1,
                                                  const float* __restrict__ cntf,
                                                  bf16_t* __restrict__ y2b,
                                                  bf16_t* __restrict__ qb,
                                                  bf16_t* __restrict__ kb,
                                                  bf16_t* __restrict__ vtb) {
  // XCD-aware swizzle: each XCD gets 8 consecutive mt row-tiles with all 42 nt
  const int bid = blockIdx.x;
  const int xcd = bid & 7, j = bid >> 3;      // j in 0..335
  const int mt = xcd * 8 + j / 42;            // 0..63
  const int nt = j % 42;                      // 0..41
  const int tid = threadIdx.x;
  const int w = tid >> 6, l = tid & 63;
  const int lq = l >> 4, lr = l & 15;

  __shared__ bf16_t lA[128 * 32];
  __shared__ bf16_t lB[128 * 32];

  f32x4 acc[4][4] = {};
  const int mwave = (w & 1) * 64, nwave = (w >> 1) * 64;
  const int srow = (w << 4) + (l >> 2);       // 0..63 within half-tile
  const int scol = (l & 3) * 8;               // bf16 elems

  for (int k0 = 0; k0 < DIM; k0 += 32) {
#pragma unroll
    for (int i = 0; i < 2; i++) {
      int row = i * 64 + srow;
      async_copy16(ytil + (size_t)(mt * 128 + row) * DIM + k0 + scol,
                   lA + (i * 64 + (w << 4)) * 32);
      async_copy16(w1b + (size_t)(nt * 128 + row) * DIM + k0 + scol,
                   lB + (i * 64 + (w << 4)) * 32);
    }
    __syncthreads();
    bf16x8 af[4], bfr[4];
#pragma unroll
    for (int mi = 0; mi < 4; mi++)
      af[mi] = *(const bf16x8*)(lA + (mwave + mi * 16 + lr) * 32 + lq * 8);
#pragma unroll
    for (int ni = 0; ni < 4; ni++)
      bfr[ni] = *(const bf16x8*)(lB + (nwave + ni * 16 + lr) * 32 + lq * 8);
#pragma unroll
    for (int mi = 0; mi < 4; mi++)
#pragma unroll
      for (int ni = 0; ni < 4; ni++)
        acc[mi][ni] = __builtin_amdgcn_mfma_f32_16x16x32_bf16(af[mi], bfr[ni], acc[mi][ni], 0, 0, 0);
    __syncthreads();
  }

#pragma unroll
  for (int mi = 0; mi < 4; mi++) {
    int row0 = mt * 128 + mwave + mi * 16 + lq * 4;
    float cnt[4];
#pragma unroll
    for (int r = 0; r < 4; r++) cnt[r] = cntf[row0 + r];
#pragma unroll
    for (int ni = 0; ni < 4; ni++) {
      int col = nt * 128 + nwave + ni * 16 + lr;
      float bias = b1[col];
      if (col < MLP_HID) {
#pragma unroll
        for (int r = 0; r < 4; r++) {
          float v = acc[mi][ni][r] + cnt[r] * bias;
          float g = 0.5f * v * (1.0f + erff(v * 0.70710678118654752f));
          y2b[(size_t)(row0 + r) * FC2_IN + col] = (bf16_t)g;
        }
      } else {
        int part = col - MLP_HID;
        int comp = (part >= 1536) ? 2 : (part >= 768) ? 1 : 0;
        int rem = part - comp * 768;
        int hh = rem >> 6, d = rem & 63;
#pragma unroll
        for (int r = 0; r < 4; r++) {
          float v = acc[mi][ni][r] + cnt[r] * bias;
          int t = row0 + r;
          int b = t >> 10, n = t & 1023;
          size_t base = (size_t)(b * NH + hh);
          if (comp == 0)      qb[(base * 1024 + n) * HD + d] = (bf16_t)v;
          else if (comp == 1) kb[(base * 1024 + n) * HD + d] = (bf16_t)v;
          else                vtb[(base * HD + d) * 1024 + n] = (bf16_t)v;
        }
      }
    }
  }
}

// ---------------- flash attention, writes attn part of y2 ----------------
__global__ __launch_bounds__(256) void attn_kernel(const bf16_t* __restrict__ qb,
                                                   const bf16_t* __restrict__ kb,
                                                   const bf16_t* __restrict__ vtb,
                                                   bf16_t* __restrict__ y2b) {
  const int bh = blockIdx.y;
  const int qt = blockIdx.x;
  const int tid = threadIdx.x;
  const int w = tid >> 6, l = tid & 63, lq = l >> 4, lr = l & 15;

  __shared__ bf16_t lK[64 * 72];
  __shared__ bf16_t lV[64 * 72];
  __shared__ bf16_t lP[4][16 * 72];

  const bf16_t* qbase = qb + (size_t)bh * 1024 * HD;
  const bf16_t* kbase = kb + (size_t)bh * 1024 * HD;
  const bf16_t* vbase = vtb + (size_t)bh * HD * 1024;

  bf16x8 qf[2];
  int qrow = qt * 64 + w * 16 + lr;
#pragma unroll
  for (int s = 0; s < 2; s++)
    qf[s] = *(const bf16x8*)(qbase + (size_t)qrow * HD + s * 32 + lq * 8);

  f32x4 oacc[4] = {};
  float mrow[4], lrow[4];
#pragma unroll
  for (int r = 0; r < 4; r++) { mrow[r] = -1e30f; lrow[r] = 0.f; }

  for (int kt = 0; kt < 16; kt++) {
#pragma unroll
    for (int i = 0; i < 2; i++) {
      int chunk = i * 256 + tid;
      int row = chunk >> 3, c = chunk & 7;
      *(float4*)(lK + row * 72 + c * 8) =
          *(const float4*)(kbase + (size_t)(kt * 64 + row) * HD + c * 8);
      *(float4*)(lV + row * 72 + c * 8) =
          *(const float4*)(vbase + (size_t)row * 1024 + kt * 64 + c * 8);
    }
    __syncthreads();

    f32x4 sacc[4] = {};
#pragma unroll
    for (int kbq = 0; kbq < 4; kbq++)
#pragma unroll
      for (int s = 0; s < 2; s++) {
        bf16x8 kf = *(const bf16x8*)(lK + (kbq * 16 + lr) * 72 + s * 32 + lq * 8);
        sacc[kbq] = __builtin_amdgcn_mfma_f32_16x16x32_bf16(qf[s], kf, sacc[kbq], 0, 0, 0);
      }

    float sv[4][4];
    float tmax[4] = {-1e30f, -1e30f, -1e30f, -1e30f};
#pragma unroll
    for (int kbq = 0; kbq < 4; kbq++)
#pragma unroll
      for (int r = 0; r < 4; r++) {
        sv[kbq][r] = sacc[kbq][r] * 0.125f;
        tmax[r] = fmaxf(tmax[r], sv[kbq][r]);
      }
#pragma unroll
    for (int off = 1; off < 16; off <<= 1)
#pragma unroll
      for (int r = 0; r < 4; r++) tmax[r] = fmaxf(tmax[r], __shfl_xor(tmax[r], off));

    float alpha[4], psum[4] = {0.f, 0.f, 0.f, 0.f};
#pragma unroll
    for (int r = 0; r < 4; r++) {
      float mnew = fmaxf(mrow[r], tmax[r]);
      alpha[r] = expf(mrow[r] - mnew);
      mrow[r] = mnew;
    }
    float pv[4][4];
#pragma unroll
    for (int kbq = 0; kbq < 4; kbq++)
#pragma unroll
      for (int r = 0; r < 4; r++) {
        pv[kbq][r] = expf(sv[kbq][r] - mrow[r]);
        psum[r] += pv[kbq][r];
      }
#pragma unroll
    for (int off = 1; off < 16; off <<= 1)
#pragma unroll
      for (int r = 0; r < 4; r++) psum[r] += __shfl_xor(psum[r], off);
#pragma unroll
    for (int r = 0; r < 4; r++) lrow[r] = lrow[r] * alpha[r] + psum[r];
#pragma unroll
    for (int nb = 0; nb < 4; nb++)
#pragma unroll
      for (int r = 0; r < 4; r++) oacc[nb][r] *= alpha[r];

#pragma unroll
    for (int kbq = 0; kbq < 4; kbq++)
#pragma unroll
      for (int r = 0; r < 4; r++)
        lP[w][(lq * 4 + r) * 72 + kbq * 16 + lr] = (bf16_t)pv[kbq][r];
    __syncthreads();

    bf16x8 pf[2];
#pragma unroll
    for (int s = 0; s < 2; s++)
      pf[s] = *(const bf16x8*)(&lP[w][lr * 72 + s * 32 + lq * 8]);

#pragma unroll
    for (int nb = 0; nb < 4; nb++)
#pragma unroll
      for (int s = 0; s < 2; s++) {
        bf16x8 vf = *(const bf16x8*)(lV + (nb * 16 + lr) * 72 + s * 32 + lq * 8);
        oacc[nb] = __builtin_amdgcn_mfma_f32_16x16x32_bf16(pf[s], vf, oacc[nb], 0, 0, 0);
      }
    __syncthreads();
  }

  int b = bh / NH, hh = bh % NH;
#pragma unroll
  for (int nb = 0; nb < 4; nb++)
#pragma unroll
    for (int r = 0; r < 4; r++) {
      float v = oacc[nb][r] / lrow[r];
      int tok = qt * 64 + w * 16 + lq * 4 + r;
      y2b[((size_t)(b * 1024 + tok)) * FC2_IN + MLP_HID + hh * HD + nb * 16 + lr] = (bf16_t)v;
    }
}

// ---------------- FC2 dense fused: out = x + Sum_halves G_seg(col) * (y2 @ w2^T + b2) ----------------
__global__ __launch_bounds__(256) void fc2_kernel(const bf16_t* __restrict__ y2b,
                                                  const bf16_t* __restrict__ w2b,
                                                  const float* __restrict__ b2,
                                                  const float* __restrict__ g4,
                                                  const float* __restrict__ x,
                                                  float* __restrict__ out) {
  // XCD-aware swizzle: each XCD gets 8 consecutive mt row-tiles with all 12 ct
  const int bid = blockIdx.x;
  const int xcd = bid & 7, j = bid >> 3;      // j in 0..95
  const int mt = xcd * 8 + j / 12;            // 0..63
  const int ct = j % 12;                      // 0..11
  const int tid = threadIdx.x;
  const int w = tid >> 6, l = tid & 63;
  const int lq = l >> 4, lr = l & 15;

  __shared__ bf16_t lA[128 * 32];
  __shared__ bf16_t lB[128 * 32];

  f32x4 acc[2][4][2] = {};
  const int mwave = (w & 1) * 64, nwave = (w >> 1) * 32;
  const int srow = (w << 4) + (l >> 2);
  const int scol = (l & 3) * 8;

  for (int k0 = 0; k0 < FC2_IN; k0 += 32) {
#pragma unroll
    for (int i = 0; i < 2; i++) {
      async_copy16(y2b + (size_t)(mt * 128 + i * 64 + srow) * FC2_IN + k0 + scol,
                   lA + (i * 64 + (w << 4)) * 32);
      // rows 0..63 = half0 (w2 rows ct*64+r), rows 64..127 = half1 (w2 rows 768+ct*64+r)
      async_copy16(w2b + (size_t)(i * 768 + ct * 64 + srow) * FC2_IN + k0 + scol,
                   lB + (i * 64 + (w << 4)) * 32);
    }
    __syncthreads();
    bf16x8 af[4], bfr[2][2];
#pragma unroll
    for (int mi = 0; mi < 4; mi++)
      af[mi] = *(const bf16x8*)(lA + (mwave + mi * 16 + lr) * 32 + lq * 8);
#pragma unroll
    for (int h = 0; h < 2; h++)
#pragma unroll
      for (int ni = 0; ni < 2; ni++)
        bfr[h][ni] = *(const bf16x8*)(lB + (h * 64 + nwave + ni * 16 + lr) * 32 + lq * 8);
#pragma unroll
    for (int h = 0; h < 2; h++)
#pragma unroll
      for (int mi = 0; mi < 4; mi++)
#pragma unroll
        for (int ni = 0; ni < 2; ni++)
          acc[h][mi][ni] = __builtin_amdgcn_mfma_f32_16x16x32_bf16(af[mi], bfr[h][ni], acc[h][mi][ni], 0, 0, 0);
    __syncthreads();
  }

#pragma unroll
  for (int mi = 0; mi < 4; mi++) {
    int row0 = mt * 128 + mwave + mi * 16 + lq * 4;
    float4 G[4];
#pragma unroll
    for (int r = 0; r < 4; r++) G[r] = ((const float4*)g4)[row0 + r];
#pragma unroll
    for (int ni = 0; ni < 2; ni++) {
      int col = ct * 64 + nwave + ni * 16 + lr;   // 0..767
      float b20 = b2[col], b21 = b2[768 + col];
#pragma unroll
      for (int r = 0; r < 4; r++) {
        float gw = (col < 96) ? G[r].x : (col < 192) ? G[r].y : (col < 384) ? G[r].z : G[r].w;
        float o = (acc[0][mi][ni][r] + b20) + (acc[1][mi][ni][r] + b21);
        size_t idx = (size_t)(row0 + r) * DIM + col;
        out[idx] = x[idx] + gw * o;
      }
    }
  }
}

extern "C" void kernel_launch(void* const* d_in, const int* in_sizes, int n_in,
                              void* d_out, int out_size, void* d_ws, size_t ws_size,
                              hipStream_t stream) {
  const float* x     = (const float*)d_in[0];
  const float* wr    = (const float*)d_in[1];
  const float* gamma = (const float*)d_in[2];
  const float* beta  = (const float*)d_in[3];
  const float* w1    = (const float*)d_in[4];
  const float* b1    = (const float*)d_in[5];
  const float* w2    = (const float*)d_in[6];
  const float* b2    = (const float*)d_in[7];
  float* out = (float*)d_out;

  char* ws = (char*)d_ws;
  float*  probs    = (float*)(ws + 0);            // 131072
  float*  gate_tok = (float*)(ws + 131072);       // 131072
  float*  cntf     = (float*)(ws + 262144);       // 32768
  float*  g4       = (float*)(ws + 294912);       // 131072
  bf16_t* w1b      = (bf16_t*)(ws + 425984);      // 8257536
  bf16_t* w2b      = (bf16_t*)(ws + 8683520);     // 11796480
  bf16_t* ytil     = (bf16_t*)(ws + 20480000);    // 12582912
  bf16_t* y2b      = (bf16_t*)(ws + 33062912);    // 62914560
  bf16_t* qb       = (bf16_t*)(ws + 95977472);    // 12582912
  bf16_t* kb       = (bf16_t*)(ws + 108560384);   // 12582912
  bf16_t* vtb      = (bf16_t*)(ws + 121143296);   // 12582912

  cast_w_kernel<<<2048, 256, 0, stream>>>(w1, w2, w1b, w2b);
  router_kernel<<<2048, 256, 0, stream>>>(x, wr, probs);
  rank_kernel<<<dim3(4, 32), 256, 0, stream>>>(probs, gate_tok);
  ln_kernel<<<2048, 256, 0, stream>>>(x, gamma, beta, gate_tok, ytil, cntf, g4);
  fc1_kernel<<<2688, 256, 0, stream>>>(ytil, w1b, b1, cntf, y2b, qb, kb, vtb);
  attn_kernel<<<dim3(16, 96), 256, 0, stream>>>(qb, kb, vtb, y2b);
  fc2_kernel<<<768, 256, 0, stream>>>(y2b, w2b, b2, g4, x, out);
}

// Round 4
// 548.215 us; speedup vs baseline: 1.5716x; 1.0147x over previous
//
#include <hip/hip_runtime.h>
#include <math.h>

typedef __bf16 bf16_t;
typedef __bf16 bf16x8 __attribute__((ext_vector_type(8)));
typedef float f32x4 __attribute__((ext_vector_type(4)));

#define DIM 768
#define NE 4
#define NH 12
#define HD 64
#define MLP_HID 3072
#define FC1_OUT 5376
#define FC2_IN 3840
#define CAP 512

__device__ __forceinline__ void async_copy16(const void* g, void* l) {
  __builtin_amdgcn_global_load_lds((const __attribute__((address_space(1))) void*)g,
                                   (__attribute__((address_space(3))) void*)l, 16, 0, 0);
}

// ---------------- weight cast fp32 -> bf16 ----------------
__global__ __launch_bounds__(256) void cast_w_kernel(const float* __restrict__ w1,
                                                     const float* __restrict__ w2,
                                                     bf16_t* __restrict__ w1b,
                                                     bf16_t* __restrict__ w2b) {
  const int N1 = FC1_OUT * DIM;
  const int N2 = 1536 * FC2_IN;
  for (int i = blockIdx.x * 256 + threadIdx.x; i < N1 + N2; i += gridDim.x * 256) {
    if (i < N1) w1b[i] = (bf16_t)w1[i];
    else        w2b[i - N1] = (bf16_t)w2[i - N1];
  }
}

// ---------------- router: logits + softmax (fp32 exact) ----------------
__global__ __launch_bounds__(256) void router_kernel(const float* __restrict__ x,
                                                     const float* __restrict__ wr,
                                                     float* __restrict__ probs) {
  int t = blockIdx.x * 4 + (threadIdx.x >> 6);
  int l = threadIdx.x & 63;
  const float* xr = x + (size_t)t * DIM;
  float a0 = 0.f, a1 = 0.f, a2 = 0.f, a3 = 0.f;
#pragma unroll
  for (int i = 0; i < 12; i++) {
    int d = l + i * 64;
    float xv = xr[d];
    a0 += xv * wr[d];
    a1 += xv * wr[DIM + d];
    a2 += xv * wr[2 * DIM + d];
    a3 += xv * wr[3 * DIM + d];
  }
#pragma unroll
  for (int off = 32; off > 0; off >>= 1) {
    a0 += __shfl_down(a0, off);
    a1 += __shfl_down(a1, off);
    a2 += __shfl_down(a2, off);
    a3 += __shfl_down(a3, off);
  }
  if (l == 0) {
    float m = fmaxf(fmaxf(a0, a1), fmaxf(a2, a3));
    float e0 = expf(a0 - m), e1 = expf(a1 - m), e2 = expf(a2 - m), e3 = expf(a3 - m);
    float inv = 1.0f / (e0 + e1 + e2 + e3);
    int b = t >> 10, n = t & 1023;
    probs[(b * NE + 0) * 1024 + n] = e0 * inv;
    probs[(b * NE + 1) * 1024 + n] = e1 * inv;
    probs[(b * NE + 2) * 1024 + n] = e2 * inv;
    probs[(b * NE + 3) * 1024 + n] = e3 * inv;
  }
}

// ---------------- exact top-k membership via ranking ----------------
__global__ __launch_bounds__(256) void rank_kernel(const float* __restrict__ probs,
                                                   float* __restrict__ gate_tok) {
  int be = blockIdx.y;
  __shared__ float p[1024];
  for (int i = threadIdx.x; i < 1024; i += 256) p[i] = probs[be * 1024 + i];
  __syncthreads();
  int n = blockIdx.x * 256 + threadIdx.x;
  float pn = p[n];
  int rank = 0;
  for (int j = 0; j < 1024; j++) {
    float pj = p[j];
    rank += (pj > pn) || (pj == pn && j < n);
  }
  int b = be >> 2, e = be & 3;
  gate_tok[(size_t)((b << 10) + n) * 4 + e] = (rank < CAP) ? pn : 0.0f;
}

// ---------------- LayerNorm + segment-count scaling -> bf16; emit gate suffix sums ----------------
__global__ __launch_bounds__(256) void ln_kernel(const float* __restrict__ x,
                                                 const float* __restrict__ gamma,
                                                 const float* __restrict__ beta,
                                                 const float* __restrict__ gate_tok,
                                                 bf16_t* __restrict__ ytil,
                                                 float* __restrict__ cntf,
                                                 float* __restrict__ g4) {
  int t = blockIdx.x * 4 + (threadIdx.x >> 6);
  int l = threadIdx.x & 63;
  float4 gg = ((const float4*)gate_tok)[t];
  float s0 = (gg.x > 0.f) ? 1.f : 0.f;
  float s1 = (gg.y > 0.f) ? 1.f : 0.f;
  float s2 = (gg.z > 0.f) ? 1.f : 0.f;
  float s3 = (gg.w > 0.f) ? 1.f : 0.f;
  float c3 = s3, c2 = c3 + s2, c1 = c2 + s1, c0 = c1 + s0;
  if (l == 0) {
    cntf[t] = c0;
    float4 G;
    G.x = gg.x + gg.y + gg.z + gg.w;
    G.y = gg.y + gg.z + gg.w;
    G.z = gg.z + gg.w;
    G.w = gg.w;
    ((float4*)g4)[t] = G;
  }
  const float* xr = x + (size_t)t * DIM;
  float v[12];
  float s = 0.f, sq = 0.f;
#pragma unroll
  for (int i = 0; i < 12; i++) {
    v[i] = xr[l + i * 64];
    s += v[i];
    sq += v[i] * v[i];
  }
#pragma unroll
  for (int off = 1; off < 64; off <<= 1) {
    s += __shfl_xor(s, off);
    sq += __shfl_xor(sq, off);
  }
  float mean = s * (1.0f / DIM);
  float var = sq * (1.0f / DIM) - mean * mean;
  float rs = rsqrtf(var + 1e-6f);
#pragma unroll
  for (int i = 0; i < 12; i++) {
    int d = l + i * 64;
    float cf = (d < 96) ? c0 : (d < 192) ? c1 : (d < 384) ? c2 : c3;
    ytil[(size_t)t * DIM + d] = (bf16_t)(((v[i] - mean) * rs * gamma[d] + beta[d]) * cf);
  }
}

// ---------------- FC1 dense: [8192,5376] = ytil @ w1^T + cnt*b1; epilogue gelu / qkv split ----------------
// BK=64, XOR-swizzled async staging: chunk=8 rows x 128B; lane l -> row l>>3, colblock (l&7)^((l>>3)&7)
__global__ __launch_bounds__(256) void fc1_kernel(const bf16_t* __restrict__ ytil,
                                                  const bf16_t* __restrict__ w1b,
                                                  const float* __restrict__ b1,
                                                  const float* __restrict__ cntf,
                                                  bf16_t* __restrict__ y2b,
                                                  bf16_t* __restrict__ qb,
                                                  bf16_t* __restrict__ kb,
                                                  bf16_t* __restrict__ vtb) {
  const int bid = blockIdx.x;
  const int xcd = bid & 7, j = bid >> 3;
  const int mt = xcd * 8 + j / 42;
  const int nt = j % 42;
  const int tid = threadIdx.x;
  const int w = tid >> 6, l = tid & 63;
  const int lq = l >> 4, lr = l & 15;

  __shared__ __align__(16) bf16_t lA[128 * 64];
  __shared__ __align__(16) bf16_t lB[128 * 64];

  f32x4 acc[4][4] = {};
  const int mwave = (w & 1) * 64, nwave = (w >> 1) * 64;
  const int crow = l >> 3;                     // row within chunk
  const int cbg = (l & 7) ^ (crow & 7);        // swizzled global colblock

  for (int k0 = 0; k0 < DIM; k0 += 64) {
#pragma unroll
    for (int i = 0; i < 4; i++) {
      int c = w * 4 + i;                       // chunk 0..15
      int row = c * 8 + crow;
      async_copy16(ytil + (size_t)(mt * 128 + row) * DIM + k0 + cbg * 8, lA + c * 512);
      async_copy16(w1b + (size_t)(nt * 128 + row) * DIM + k0 + cbg * 8, lB + c * 512);
    }
    __syncthreads();
#pragma unroll
    for (int ks = 0; ks < 2; ks++) {
      const int cbA = ((ks * 4 + lq) ^ (lr & 7)) * 8;
      bf16x8 af[4], bfr[4];
#pragma unroll
      for (int mi = 0; mi < 4; mi++)
        af[mi] = *(const bf16x8*)(lA + (mwave + mi * 16 + lr) * 64 + cbA);
#pragma unroll
      for (int ni = 0; ni < 4; ni++)
        bfr[ni] = *(const bf16x8*)(lB + (nwave + ni * 16 + lr) * 64 + cbA);
#pragma unroll
      for (int mi = 0; mi < 4; mi++)
#pragma unroll
        for (int ni = 0; ni < 4; ni++)
          acc[mi][ni] = __builtin_amdgcn_mfma_f32_16x16x32_bf16(af[mi], bfr[ni], acc[mi][ni], 0, 0, 0);
    }
    __syncthreads();
  }

#pragma unroll
  for (int mi = 0; mi < 4; mi++) {
    int row0 = mt * 128 + mwave + mi * 16 + lq * 4;
    float cnt[4];
#pragma unroll
    for (int r = 0; r < 4; r++) cnt[r] = cntf[row0 + r];
#pragma unroll
    for (int ni = 0; ni < 4; ni++) {
      int col = nt * 128 + nwave + ni * 16 + lr;
      float bias = b1[col];
      if (col < MLP_HID) {
#pragma unroll
        for (int r = 0; r < 4; r++) {
          float v = acc[mi][ni][r] + cnt[r] * bias;
          float g = 0.5f * v * (1.0f + erff(v * 0.70710678118654752f));
          y2b[(size_t)(row0 + r) * FC2_IN + col] = (bf16_t)g;
        }
      } else {
        int part = col - MLP_HID;
        int comp = (part >= 1536) ? 2 : (part >= 768) ? 1 : 0;
        int rem = part - comp * 768;
        int hh = rem >> 6, d = rem & 63;
#pragma unroll
        for (int r = 0; r < 4; r++) {
          float v = acc[mi][ni][r] + cnt[r] * bias;
          int t = row0 + r;
          int b = t >> 10, n = t & 1023;
          size_t base = (size_t)(b * NH + hh);
          if (comp == 0)      qb[(base * 1024 + n) * HD + d] = (bf16_t)v;
          else if (comp == 1) kb[(base * 1024 + n) * HD + d] = (bf16_t)v;
          else                vtb[(base * HD + d) * 1024 + n] = (bf16_t)v;
        }
      }
    }
  }
}

// ---------------- flash attention, writes attn part of y2 ----------------
// K/V tiles: async swizzled staging (64x64, unpadded); lP wave-private (no barrier needed)
__global__ __launch_bounds__(256) void attn_kernel(const bf16_t* __restrict__ qb,
                                                   const bf16_t* __restrict__ kb,
                                                   const bf16_t* __restrict__ vtb,
                                                   bf16_t* __restrict__ y2b) {
  const int bh = blockIdx.y;
  const int qt = blockIdx.x;
  const int tid = threadIdx.x;
  const int w = tid >> 6, l = tid & 63, lq = l >> 4, lr = l & 15;

  __shared__ __align__(16) bf16_t lK[64 * 64];
  __shared__ __align__(16) bf16_t lV[64 * 64];
  __shared__ __align__(16) bf16_t lP[4][16 * 72];

  const bf16_t* qbase = qb + (size_t)bh * 1024 * HD;
  const bf16_t* kbase = kb + (size_t)bh * 1024 * HD;
  const bf16_t* vbase = vtb + (size_t)bh * HD * 1024;

  bf16x8 qf[2];
  int qrow = qt * 64 + w * 16 + lr;
#pragma unroll
  for (int s = 0; s < 2; s++)
    qf[s] = *(const bf16x8*)(qbase + (size_t)qrow * HD + s * 32 + lq * 8);

  f32x4 oacc[4] = {};
  float mrow[4], lrow[4];
#pragma unroll
  for (int r = 0; r < 4; r++) { mrow[r] = -1e30f; lrow[r] = 0.f; }

  const int crow = l >> 3;
  const int cbg = (l & 7) ^ (crow & 7);

  for (int kt = 0; kt < 16; kt++) {
#pragma unroll
    for (int i = 0; i < 2; i++) {
      int c = w * 2 + i;                        // chunk 0..7
      int row = c * 8 + crow;
      async_copy16(kbase + (size_t)(kt * 64 + row) * HD + cbg * 8, lK + c * 512);
      async_copy16(vbase + (size_t)row * 1024 + kt * 64 + cbg * 8, lV + c * 512);
    }
    __syncthreads();

    f32x4 sacc[4] = {};
#pragma unroll
    for (int s = 0; s < 2; s++) {
      const int cb = ((s * 4 + lq) ^ (lr & 7)) * 8;
#pragma unroll
      for (int kbq = 0; kbq < 4; kbq++) {
        bf16x8 kf = *(const bf16x8*)(lK + (kbq * 16 + lr) * 64 + cb);
        sacc[kbq] = __builtin_amdgcn_mfma_f32_16x16x32_bf16(qf[s], kf, sacc[kbq], 0, 0, 0);
      }
    }

    float sv[4][4];
    float tmax[4] = {-1e30f, -1e30f, -1e30f, -1e30f};
#pragma unroll
    for (int kbq = 0; kbq < 4; kbq++)
#pragma unroll
      for (int r = 0; r < 4; r++) {
        sv[kbq][r] = sacc[kbq][r] * 0.125f;
        tmax[r] = fmaxf(tmax[r], sv[kbq][r]);
      }
#pragma unroll
    for (int off = 1; off < 16; off <<= 1)
#pragma unroll
      for (int r = 0; r < 4; r++) tmax[r] = fmaxf(tmax[r], __shfl_xor(tmax[r], off));

    float alpha[4], psum[4] = {0.f, 0.f, 0.f, 0.f};
#pragma unroll
    for (int r = 0; r < 4; r++) {
      float mnew = fmaxf(mrow[r], tmax[r]);
      alpha[r] = expf(mrow[r] - mnew);
      mrow[r] = mnew;
    }
    float pv[4][4];
#pragma unroll
    for (int kbq = 0; kbq < 4; kbq++)
#pragma unroll
      for (int r = 0; r < 4; r++) {
        pv[kbq][r] = expf(sv[kbq][r] - mrow[r]);
        psum[r] += pv[kbq][r];
      }
#pragma unroll
    for (int off = 1; off < 16; off <<= 1)
#pragma unroll
      for (int r = 0; r < 4; r++) psum[r] += __shfl_xor(psum[r], off);
#pragma unroll
    for (int r = 0; r < 4; r++) lrow[r] = lrow[r] * alpha[r] + psum[r];
#pragma unroll
    for (int nb = 0; nb < 4; nb++)
#pragma unroll
      for (int r = 0; r < 4; r++) oacc[nb][r] *= alpha[r];

    // P: C-layout -> wave-private LDS slab -> A-layout (no cross-wave barrier needed)
#pragma unroll
    for (int kbq = 0; kbq < 4; kbq++)
#pragma unroll
      for (int r = 0; r < 4; r++)
        lP[w][(lq * 4 + r) * 72 + kbq * 16 + lr] = (bf16_t)pv[kbq][r];

    bf16x8 pf[2];
#pragma unroll
    for (int s = 0; s < 2; s++)
      pf[s] = *(const bf16x8*)(&lP[w][lr * 72 + s * 32 + lq * 8]);

#pragma unroll
    for (int s = 0; s < 2; s++) {
      const int cb = ((s * 4 + lq) ^ (lr & 7)) * 8;
#pragma unroll
      for (int nb = 0; nb < 4; nb++) {
        bf16x8 vf = *(const bf16x8*)(lV + (nb * 16 + lr) * 64 + cb);
        oacc[nb] = __builtin_amdgcn_mfma_f32_16x16x32_bf16(pf[s], vf, oacc[nb], 0, 0, 0);
      }
    }
    __syncthreads();
  }

  int b = bh / NH, hh = bh % NH;
#pragma unroll
  for (int nb = 0; nb < 4; nb++)
#pragma unroll
    for (int r = 0; r < 4; r++) {
      float v = oacc[nb][r] / lrow[r];
      int tok = qt * 64 + w * 16 + lq * 4 + r;
      y2b[((size_t)(b * 1024 + tok)) * FC2_IN + MLP_HID + hh * HD + nb * 16 + lr] = (bf16_t)v;
    }
}

// ---------------- FC2 dense fused: out = x + Sum_halves G_seg(col) * (y2 @ w2^T + b2) ----------------
__global__ __launch_bounds__(256) void fc2_kernel(const bf16_t* __restrict__ y2b,
                                                  const bf16_t* __restrict__ w2b,
                                                  const float* __restrict__ b2,
                                                  const float* __restrict__ g4,
                                                  const float* __restrict__ x,
                                                  float* __restrict__ out) {
  const int bid = blockIdx.x;
  const int xcd = bid & 7, j = bid >> 3;
  const int mt = xcd * 8 + j / 12;
  const int ct = j % 12;
  const int tid = threadIdx.x;
  const int w = tid >> 6, l = tid & 63;
  const int lq = l >> 4, lr = l & 15;

  __shared__ __align__(16) bf16_t lA[128 * 64];
  __shared__ __align__(16) bf16_t lB[128 * 64];

  f32x4 acc[2][4][2] = {};
  const int mwave = (w & 1) * 64, nwave = (w >> 1) * 32;
  const int crow = l >> 3;
  const int cbg = (l & 7) ^ (crow & 7);

  for (int k0 = 0; k0 < FC2_IN; k0 += 64) {
#pragma unroll
    for (int i = 0; i < 4; i++) {
      int c = w * 4 + i;                       // chunk 0..15
      int row = c * 8 + crow;                  // 0..127
      async_copy16(y2b + (size_t)(mt * 128 + row) * FC2_IN + k0 + cbg * 8, lA + c * 512);
      int grow = ((row >> 6) * 768) + ct * 64 + (row & 63);   // half0 / half1 of w2
      async_copy16(w2b + (size_t)grow * FC2_IN + k0 + cbg * 8, lB + c * 512);
    }
    __syncthreads();
#pragma unroll
    for (int ks = 0; ks < 2; ks++) {
      const int cbA = ((ks * 4 + lq) ^ (lr & 7)) * 8;
      bf16x8 af[4], bfr[2][2];
#pragma unroll
      for (int mi = 0; mi < 4; mi++)
        af[mi] = *(const bf16x8*)(lA + (mwave + mi * 16 + lr) * 64 + cbA);
#pragma unroll
      for (int h = 0; h < 2; h++)
#pragma unroll
        for (int ni = 0; ni < 2; ni++)
          bfr[h][ni] = *(const bf16x8*)(lB + (h * 64 + nwave + ni * 16 + lr) * 64 + cbA);
#pragma unroll
      for (int h = 0; h < 2; h++)
#pragma unroll
        for (int mi = 0; mi < 4; mi++)
#pragma unroll
          for (int ni = 0; ni < 2; ni++)
            acc[h][mi][ni] = __builtin_amdgcn_mfma_f32_16x16x32_bf16(af[mi], bfr[h][ni], acc[h][mi][ni], 0, 0, 0);
    }
    __syncthreads();
  }

#pragma unroll
  for (int mi = 0; mi < 4; mi++) {
    int row0 = mt * 128 + mwave + mi * 16 + lq * 4;
    float4 G[4];
#pragma unroll
    for (int r = 0; r < 4; r++) G[r] = ((const float4*)g4)[row0 + r];
#pragma unroll
    for (int ni = 0; ni < 2; ni++) {
      int col = ct * 64 + nwave + ni * 16 + lr;   // 0..767
      float b20 = b2[col], b21 = b2[768 + col];
#pragma unroll
      for (int r = 0; r < 4; r++) {
        float gw = (col < 96) ? G[r].x : (col < 192) ? G[r].y : (col < 384) ? G[r].z : G[r].w;
        float o = (acc[0][mi][ni][r] + b20) + (acc[1][mi][ni][r] + b21);
        size_t idx = (size_t)(row0 + r) * DIM + col;
        out[idx] = x[idx] + gw * o;
      }
    }
  }
}

extern "C" void kernel_launch(void* const* d_in, const int* in_sizes, int n_in,
                              void* d_out, int out_size, void* d_ws, size_t ws_size,
                              hipStream_t stream) {
  const float* x     = (const float*)d_in[0];
  const float* wr    = (const float*)d_in[1];
  const float* gamma = (const float*)d_in[2];
  const float* beta  = (const float*)d_in[3];
  const float* w1    = (const float*)d_in[4];
  const float* b1    = (const float*)d_in[5];
  const float* w2    = (const float*)d_in[6];
  const float* b2    = (const float*)d_in[7];
  float* out = (float*)d_out;

  char* ws = (char*)d_ws;
  float*  probs    = (float*)(ws + 0);            // 131072
  float*  gate_tok = (float*)(ws + 131072);       // 131072
  float*  cntf     = (float*)(ws + 262144);       // 32768
  float*  g4       = (float*)(ws + 294912);       // 131072
  bf16_t* w1b      = (bf16_t*)(ws + 425984);      // 8257536
  bf16_t* w2b      = (bf16_t*)(ws + 8683520);     // 11796480
  bf16_t* ytil     = (bf16_t*)(ws + 20480000);    // 12582912
  bf16_t* y2b      = (bf16_t*)(ws + 33062912);    // 62914560
  bf16_t* qb       = (bf16_t*)(ws + 95977472);    // 12582912
  bf16_t* kb       = (bf16_t*)(ws + 108560384);   // 12582912
  bf16_t* vtb      = (bf16_t*)(ws + 121143296);   // 12582912

  cast_w_kernel<<<2048, 256, 0, stream>>>(w1, w2, w1b, w2b);
  router_kernel<<<2048, 256, 0, stream>>>(x, wr, probs);
  rank_kernel<<<dim3(4, 32), 256, 0, stream>>>(probs, gate_tok);
  ln_kernel<<<2048, 256, 0, stream>>>(x, gamma, beta, gate_tok, ytil, cntf, g4);
  fc1_kernel<<<2688, 256, 0, stream>>>(ytil, w1b, b1, cntf, y2b, qb, kb, vtb);
  attn_kernel<<<dim3(16, 96), 256, 0, stream>>>(qb, kb, vtb, y2b);
  fc2_kernel<<<768, 256, 0, stream>>>(y2b, w2b, b2, g4, x, out);
}

// Round 5
// 509.254 us; speedup vs baseline: 1.6918x; 1.0765x over previous
//
#include <hip/hip_runtime.h>
#include <math.h>

typedef __bf16 bf16_t;
typedef __bf16 bf16x8 __attribute__((ext_vector_type(8)));
typedef float f32x4 __attribute__((ext_vector_type(4)));

#define DIM 768
#define NE 4
#define NH 12
#define HD 64
#define MLP_HID 3072
#define FC1_OUT 5376
#define FC2_IN 3840
#define CAP 512
#define LOG2E 1.44269504088896340736f

__device__ __forceinline__ void async_copy16(const void* g, void* l) {
  __builtin_amdgcn_global_load_lds((const __attribute__((address_space(1))) void*)g,
                                   (__attribute__((address_space(3))) void*)l, 16, 0, 0);
}

// fast exact-enough GELU: A&S 7.1.26 erf (abs err 1.5e-7) + native exp
__device__ __forceinline__ float gelu_f(float v) {
  float x = fabsf(v) * 0.70710678118654752f;
  float t = __builtin_amdgcn_rcpf(1.0f + 0.3275911f * x);
  float poly = ((((1.061405429f * t - 1.453152027f) * t + 1.421413741f) * t
                 - 0.284496736f) * t + 0.254829592f) * t;
  float e = __expf(-x * x);
  float erfv = copysignf(1.0f - poly * e, v);
  return 0.5f * v * (1.0f + erfv);
}

// ---------------- weight cast fp32 -> bf16 ----------------
__global__ __launch_bounds__(256) void cast_w_kernel(const float* __restrict__ w1,
                                                     const float* __restrict__ w2,
                                                     bf16_t* __restrict__ w1b,
                                                     bf16_t* __restrict__ w2b) {
  const int N1 = FC1_OUT * DIM;
  const int N2 = 1536 * FC2_IN;
  for (int i = blockIdx.x * 256 + threadIdx.x; i < N1 + N2; i += gridDim.x * 256) {
    if (i < N1) w1b[i] = (bf16_t)w1[i];
    else        w2b[i - N1] = (bf16_t)w2[i - N1];
  }
}

// ---------------- router: logits + softmax (fp32 exact; selection-critical) ----------------
__global__ __launch_bounds__(256) void router_kernel(const float* __restrict__ x,
                                                     const float* __restrict__ wr,
                                                     float* __restrict__ probs) {
  int t = blockIdx.x * 4 + (threadIdx.x >> 6);
  int l = threadIdx.x & 63;
  const float* xr = x + (size_t)t * DIM;
  float a0 = 0.f, a1 = 0.f, a2 = 0.f, a3 = 0.f;
#pragma unroll
  for (int i = 0; i < 12; i++) {
    int d = l + i * 64;
    float xv = xr[d];
    a0 += xv * wr[d];
    a1 += xv * wr[DIM + d];
    a2 += xv * wr[2 * DIM + d];
    a3 += xv * wr[3 * DIM + d];
  }
#pragma unroll
  for (int off = 32; off > 0; off >>= 1) {
    a0 += __shfl_down(a0, off);
    a1 += __shfl_down(a1, off);
    a2 += __shfl_down(a2, off);
    a3 += __shfl_down(a3, off);
  }
  if (l == 0) {
    float m = fmaxf(fmaxf(a0, a1), fmaxf(a2, a3));
    float e0 = expf(a0 - m), e1 = expf(a1 - m), e2 = expf(a2 - m), e3 = expf(a3 - m);
    float inv = 1.0f / (e0 + e1 + e2 + e3);
    int b = t >> 10, n = t & 1023;
    probs[(b * NE + 0) * 1024 + n] = e0 * inv;
    probs[(b * NE + 1) * 1024 + n] = e1 * inv;
    probs[(b * NE + 2) * 1024 + n] = e2 * inv;
    probs[(b * NE + 3) * 1024 + n] = e3 * inv;
  }
}

// ---------------- exact top-k membership via ranking ----------------
__global__ __launch_bounds__(256) void rank_kernel(const float* __restrict__ probs,
                                                   float* __restrict__ gate_tok) {
  int be = blockIdx.y;
  __shared__ float p[1024];
  for (int i = threadIdx.x; i < 1024; i += 256) p[i] = probs[be * 1024 + i];
  __syncthreads();
  int n = blockIdx.x * 256 + threadIdx.x;
  float pn = p[n];
  int rank = 0;
  for (int j = 0; j < 1024; j++) {
    float pj = p[j];
    rank += (pj > pn) || (pj == pn && j < n);
  }
  int b = be >> 2, e = be & 3;
  gate_tok[(size_t)((b << 10) + n) * 4 + e] = (rank < CAP) ? pn : 0.0f;
}

// ---------------- LayerNorm + segment-count scaling -> bf16; emit gate suffix sums ----------------
__global__ __launch_bounds__(256) void ln_kernel(const float* __restrict__ x,
                                                 const float* __restrict__ gamma,
                                                 const float* __restrict__ beta,
                                                 const float* __restrict__ gate_tok,
                                                 bf16_t* __restrict__ ytil,
                                                 float* __restrict__ cntf,
                                                 float* __restrict__ g4) {
  int t = blockIdx.x * 4 + (threadIdx.x >> 6);
  int l = threadIdx.x & 63;
  float4 gg = ((const float4*)gate_tok)[t];
  float s0 = (gg.x > 0.f) ? 1.f : 0.f;
  float s1 = (gg.y > 0.f) ? 1.f : 0.f;
  float s2 = (gg.z > 0.f) ? 1.f : 0.f;
  float s3 = (gg.w > 0.f) ? 1.f : 0.f;
  float c3 = s3, c2 = c3 + s2, c1 = c2 + s1, c0 = c1 + s0;
  if (l == 0) {
    cntf[t] = c0;
    float4 G;
    G.x = gg.x + gg.y + gg.z + gg.w;
    G.y = gg.y + gg.z + gg.w;
    G.z = gg.z + gg.w;
    G.w = gg.w;
    ((float4*)g4)[t] = G;
  }
  const float* xr = x + (size_t)t * DIM;
  float v[12];
  float s = 0.f, sq = 0.f;
#pragma unroll
  for (int i = 0; i < 12; i++) {
    v[i] = xr[l + i * 64];
    s += v[i];
    sq += v[i] * v[i];
  }
#pragma unroll
  for (int off = 1; off < 64; off <<= 1) {
    s += __shfl_xor(s, off);
    sq += __shfl_xor(sq, off);
  }
  float mean = s * (1.0f / DIM);
  float var = sq * (1.0f / DIM) - mean * mean;
  float rs = rsqrtf(var + 1e-6f);
#pragma unroll
  for (int i = 0; i < 12; i++) {
    int d = l + i * 64;
    float cf = (d < 96) ? c0 : (d < 192) ? c1 : (d < 384) ? c2 : c3;
    ytil[(size_t)t * DIM + d] = (bf16_t)(((v[i] - mean) * rs * gamma[d] + beta[d]) * cf);
  }
}

// ---------------- FC1 dense: [8192,5376] = ytil @ w1^T + cnt*b1; epilogue gelu / qkv split ----------------
// BK=64, XOR-swizzled async staging. nt-SLOW block order: per XCD, A-stripes (1.57 MB) stay
// L2-resident; each B tile fetched once by its 8 concurrent sharers.
__global__ __launch_bounds__(256) void fc1_kernel(const bf16_t* __restrict__ ytil,
                                                  const bf16_t* __restrict__ w1b,
                                                  const float* __restrict__ b1,
                                                  const float* __restrict__ cntf,
                                                  bf16_t* __restrict__ y2b,
                                                  bf16_t* __restrict__ qb,
                                                  bf16_t* __restrict__ kb,
                                                  bf16_t* __restrict__ vtb) {
  const int bid = blockIdx.x;
  const int xcd = bid & 7, j = bid >> 3;      // j in 0..335
  const int mt = xcd * 8 + (j & 7);           // 0..63 (fast within XCD)
  const int nt = j >> 3;                      // 0..41 (slow)
  const int tid = threadIdx.x;
  const int w = tid >> 6, l = tid & 63;
  const int lq = l >> 4, lr = l & 15;

  __shared__ __align__(16) bf16_t lA[128 * 64];
  __shared__ __align__(16) bf16_t lB[128 * 64];

  f32x4 acc[4][4] = {};
  const int mwave = (w & 1) * 64, nwave = (w >> 1) * 64;
  const int crow = l >> 3;
  const int cbg = (l & 7) ^ (crow & 7);

  for (int k0 = 0; k0 < DIM; k0 += 64) {
#pragma unroll
    for (int i = 0; i < 4; i++) {
      int c = w * 4 + i;
      int row = c * 8 + crow;
      async_copy16(ytil + (size_t)(mt * 128 + row) * DIM + k0 + cbg * 8, lA + c * 512);
      async_copy16(w1b + (size_t)(nt * 128 + row) * DIM + k0 + cbg * 8, lB + c * 512);
    }
    __syncthreads();
#pragma unroll
    for (int ks = 0; ks < 2; ks++) {
      const int cbA = ((ks * 4 + lq) ^ (lr & 7)) * 8;
      bf16x8 af[4], bfr[4];
#pragma unroll
      for (int mi = 0; mi < 4; mi++)
        af[mi] = *(const bf16x8*)(lA + (mwave + mi * 16 + lr) * 64 + cbA);
#pragma unroll
      for (int ni = 0; ni < 4; ni++)
        bfr[ni] = *(const bf16x8*)(lB + (nwave + ni * 16 + lr) * 64 + cbA);
#pragma unroll
      for (int mi = 0; mi < 4; mi++)
#pragma unroll
        for (int ni = 0; ni < 4; ni++)
          acc[mi][ni] = __builtin_amdgcn_mfma_f32_16x16x32_bf16(af[mi], bfr[ni], acc[mi][ni], 0, 0, 0);
    }
    __syncthreads();
  }

#pragma unroll
  for (int mi = 0; mi < 4; mi++) {
    int row0 = mt * 128 + mwave + mi * 16 + lq * 4;
    float cnt[4];
#pragma unroll
    for (int r = 0; r < 4; r++) cnt[r] = cntf[row0 + r];
#pragma unroll
    for (int ni = 0; ni < 4; ni++) {
      int col = nt * 128 + nwave + ni * 16 + lr;
      float bias = b1[col];
      if (col < MLP_HID) {
#pragma unroll
        for (int r = 0; r < 4; r++) {
          float v = acc[mi][ni][r] + cnt[r] * bias;
          y2b[(size_t)(row0 + r) * FC2_IN + col] = (bf16_t)gelu_f(v);
        }
      } else {
        int part = col - MLP_HID;
        int comp = (part >= 1536) ? 2 : (part >= 768) ? 1 : 0;
        int rem = part - comp * 768;
        int hh = rem >> 6, d = rem & 63;
#pragma unroll
        for (int r = 0; r < 4; r++) {
          float v = acc[mi][ni][r] + cnt[r] * bias;
          int t = row0 + r;
          int b = t >> 10, n = t & 1023;
          size_t base = (size_t)(b * NH + hh);
          if (comp == 0)      qb[(base * 1024 + n) * HD + d] = (bf16_t)v;
          else if (comp == 1) kb[(base * 1024 + n) * HD + d] = (bf16_t)v;
          else                vtb[(base * HD + d) * 1024 + n] = (bf16_t)v;
        }
      }
    }
  }
}

// ---------------- flash attention (log2-domain online softmax), writes attn part of y2 ----------------
__global__ __launch_bounds__(256) void attn_kernel(const bf16_t* __restrict__ qb,
                                                   const bf16_t* __restrict__ kb,
                                                   const bf16_t* __restrict__ vtb,
                                                   bf16_t* __restrict__ y2b) {
  const int bh = blockIdx.y;
  const int qt = blockIdx.x;
  const int tid = threadIdx.x;
  const int w = tid >> 6, l = tid & 63, lq = l >> 4, lr = l & 15;

  __shared__ __align__(16) bf16_t lK[64 * 64];
  __shared__ __align__(16) bf16_t lV[64 * 64];
  __shared__ __align__(16) bf16_t lP[4][16 * 72];

  const bf16_t* qbase = qb + (size_t)bh * 1024 * HD;
  const bf16_t* kbase = kb + (size_t)bh * 1024 * HD;
  const bf16_t* vbase = vtb + (size_t)bh * HD * 1024;

  bf16x8 qf[2];
  int qrow = qt * 64 + w * 16 + lr;
#pragma unroll
  for (int s = 0; s < 2; s++)
    qf[s] = *(const bf16x8*)(qbase + (size_t)qrow * HD + s * 32 + lq * 8);

  f32x4 oacc[4] = {};
  float mrow[4], lrow[4];          // mrow in log2 units
#pragma unroll
  for (int r = 0; r < 4; r++) { mrow[r] = -1e30f; lrow[r] = 0.f; }

  const float s2 = 0.125f * LOG2E;
  const int crow = l >> 3;
  const int cbg = (l & 7) ^ (crow & 7);

  for (int kt = 0; kt < 16; kt++) {
#pragma unroll
    for (int i = 0; i < 2; i++) {
      int c = w * 2 + i;
      int row = c * 8 + crow;
      async_copy16(kbase + (size_t)(kt * 64 + row) * HD + cbg * 8, lK + c * 512);
      async_copy16(vbase + (size_t)row * 1024 + kt * 64 + cbg * 8, lV + c * 512);
    }
    __syncthreads();

    f32x4 sacc[4] = {};
#pragma unroll
    for (int s = 0; s < 2; s++) {
      const int cb = ((s * 4 + lq) ^ (lr & 7)) * 8;
#pragma unroll
      for (int kbq = 0; kbq < 4; kbq++) {
        bf16x8 kf = *(const bf16x8*)(lK + (kbq * 16 + lr) * 64 + cb);
        sacc[kbq] = __builtin_amdgcn_mfma_f32_16x16x32_bf16(qf[s], kf, sacc[kbq], 0, 0, 0);
      }
    }

    float sv[4][4];
    float tmax[4] = {-1e30f, -1e30f, -1e30f, -1e30f};
#pragma unroll
    for (int kbq = 0; kbq < 4; kbq++)
#pragma unroll
      for (int r = 0; r < 4; r++) {
        sv[kbq][r] = sacc[kbq][r] * s2;          // log2-domain score
        tmax[r] = fmaxf(tmax[r], sv[kbq][r]);
      }
#pragma unroll
    for (int off = 1; off < 16; off <<= 1)
#pragma unroll
      for (int r = 0; r < 4; r++) tmax[r] = fmaxf(tmax[r], __shfl_xor(tmax[r], off));

    float alpha[4], psum[4] = {0.f, 0.f, 0.f, 0.f};
#pragma unroll
    for (int r = 0; r < 4; r++) {
      float mnew = fmaxf(mrow[r], tmax[r]);
      alpha[r] = exp2f(mrow[r] - mnew);
      mrow[r] = mnew;
    }
    float pv[4][4];
#pragma unroll
    for (int kbq = 0; kbq < 4; kbq++)
#pragma unroll
      for (int r = 0; r < 4; r++) {
        pv[kbq][r] = exp2f(sv[kbq][r] - mrow[r]);
        psum[r] += pv[kbq][r];
      }
#pragma unroll
    for (int off = 1; off < 16; off <<= 1)
#pragma unroll
      for (int r = 0; r < 4; r++) psum[r] += __shfl_xor(psum[r], off);
#pragma unroll
    for (int r = 0; r < 4; r++) lrow[r] = lrow[r] * alpha[r] + psum[r];
#pragma unroll
    for (int nb = 0; nb < 4; nb++)
#pragma unroll
      for (int r = 0; r < 4; r++) oacc[nb][r] *= alpha[r];

    // P: C-layout -> wave-private LDS slab -> A-layout (no cross-wave barrier needed)
#pragma unroll
    for (int kbq = 0; kbq < 4; kbq++)
#pragma unroll
      for (int r = 0; r < 4; r++)
        lP[w][(lq * 4 + r) * 72 + kbq * 16 + lr] = (bf16_t)pv[kbq][r];

    bf16x8 pf[2];
#pragma unroll
    for (int s = 0; s < 2; s++)
      pf[s] = *(const bf16x8*)(&lP[w][lr * 72 + s * 32 + lq * 8]);

#pragma unroll
    for (int s = 0; s < 2; s++) {
      const int cb = ((s * 4 + lq) ^ (lr & 7)) * 8;
#pragma unroll
      for (int nb = 0; nb < 4; nb++) {
        bf16x8 vf = *(const bf16x8*)(lV + (nb * 16 + lr) * 64 + cb);
        oacc[nb] = __builtin_amdgcn_mfma_f32_16x16x32_bf16(pf[s], vf, oacc[nb], 0, 0, 0);
      }
    }
    __syncthreads();
  }

  int b = bh / NH, hh = bh % NH;
#pragma unroll
  for (int nb = 0; nb < 4; nb++)
#pragma unroll
    for (int r = 0; r < 4; r++) {
      float v = oacc[nb][r] / lrow[r];
      int tok = qt * 64 + w * 16 + lq * 4 + r;
      y2b[((size_t)(b * 1024 + tok)) * FC2_IN + MLP_HID + hh * HD + nb * 16 + lr] = (bf16_t)v;
    }
}

// ---------------- FC2 dense fused: out = x + Sum_halves G_seg(col) * (y2 @ w2^T + b2) ----------------
__global__ __launch_bounds__(256) void fc2_kernel(const bf16_t* __restrict__ y2b,
                                                  const bf16_t* __restrict__ w2b,
                                                  const float* __restrict__ b2,
                                                  const float* __restrict__ g4,
                                                  const float* __restrict__ x,
                                                  float* __restrict__ out) {
  const int bid = blockIdx.x;
  const int xcd = bid & 7, j = bid >> 3;
  const int mt = xcd * 8 + j / 12;
  const int ct = j % 12;
  const int tid = threadIdx.x;
  const int w = tid >> 6, l = tid & 63;
  const int lq = l >> 4, lr = l & 15;

  __shared__ __align__(16) bf16_t lA[128 * 64];
  __shared__ __align__(16) bf16_t lB[128 * 64];

  f32x4 acc[2][4][2] = {};
  const int mwave = (w & 1) * 64, nwave = (w >> 1) * 32;
  const int crow = l >> 3;
  const int cbg = (l & 7) ^ (crow & 7);

  for (int k0 = 0; k0 < FC2_IN; k0 += 64) {
#pragma unroll
    for (int i = 0; i < 4; i++) {
      int c = w * 4 + i;
      int row = c * 8 + crow;
      async_copy16(y2b + (size_t)(mt * 128 + row) * FC2_IN + k0 + cbg * 8, lA + c * 512);
      int grow = ((row >> 6) * 768) + ct * 64 + (row & 63);
      async_copy16(w2b + (size_t)grow * FC2_IN + k0 + cbg * 8, lB + c * 512);
    }
    __syncthreads();
#pragma unroll
    for (int ks = 0; ks < 2; ks++) {
      const int cbA = ((ks * 4 + lq) ^ (lr & 7)) * 8;
      bf16x8 af[4], bfr[2][2];
#pragma unroll
      for (int mi = 0; mi < 4; mi++)
        af[mi] = *(const bf16x8*)(lA + (mwave + mi * 16 + lr) * 64 + cbA);
#pragma unroll
      for (int h = 0; h < 2; h++)
#pragma unroll
        for (int ni = 0; ni < 2; ni++)
          bfr[h][ni] = *(const bf16x8*)(lB + (h * 64 + nwave + ni * 16 + lr) * 64 + cbA);
#pragma unroll
      for (int h = 0; h < 2; h++)
#pragma unroll
        for (int mi = 0; mi < 4; mi++)
#pragma unroll
          for (int ni = 0; ni < 2; ni++)
            acc[h][mi][ni] = __builtin_amdgcn_mfma_f32_16x16x32_bf16(af[mi], bfr[h][ni], acc[h][mi][ni], 0, 0, 0);
    }
    __syncthreads();
  }

#pragma unroll
  for (int mi = 0; mi < 4; mi++) {
    int row0 = mt * 128 + mwave + mi * 16 + lq * 4;
    float4 G[4];
#pragma unroll
    for (int r = 0; r < 4; r++) G[r] = ((const float4*)g4)[row0 + r];
#pragma unroll
    for (int ni = 0; ni < 2; ni++) {
      int col = ct * 64 + nwave + ni * 16 + lr;
      float b20 = b2[col], b21 = b2[768 + col];
#pragma unroll
      for (int r = 0; r < 4; r++) {
        float gw = (col < 96) ? G[r].x : (col < 192) ? G[r].y : (col < 384) ? G[r].z : G[r].w;
        float o = (acc[0][mi][ni][r] + b20) + (acc[1][mi][ni][r] + b21);
        size_t idx = (size_t)(row0 + r) * DIM + col;
        out[idx] = x[idx] + gw * o;
      }
    }
  }
}

extern "C" void kernel_launch(void* const* d_in, const int* in_sizes, int n_in,
                              void* d_out, int out_size, void* d_ws, size_t ws_size,
                              hipStream_t stream) {
  const float* x     = (const float*)d_in[0];
  const float* wr    = (const float*)d_in[1];
  const float* gamma = (const float*)d_in[2];
  const float* beta  = (const float*)d_in[3];
  const float* w1    = (const float*)d_in[4];
  const float* b1    = (const float*)d_in[5];
  const float* w2    = (const float*)d_in[6];
  const float* b2    = (const float*)d_in[7];
  float* out = (float*)d_out;

  char* ws = (char*)d_ws;
  float*  probs    = (float*)(ws + 0);            // 131072
  float*  gate_tok = (float*)(ws + 131072);       // 131072
  float*  cntf     = (float*)(ws + 262144);       // 32768
  float*  g4       = (float*)(ws + 294912);       // 131072
  bf16_t* w1b      = (bf16_t*)(ws + 425984);      // 8257536
  bf16_t* w2b      = (bf16_t*)(ws + 8683520);     // 11796480
  bf16_t* ytil     = (bf16_t*)(ws + 20480000);    // 12582912
  bf16_t* y2b      = (bf16_t*)(ws + 33062912);    // 62914560
  bf16_t* qb       = (bf16_t*)(ws + 95977472);    // 12582912
  bf16_t* kb       = (bf16_t*)(ws + 108560384);   // 12582912
  bf16_t* vtb      = (bf16_t*)(ws + 121143296);   // 12582912

  cast_w_kernel<<<2048, 256, 0, stream>>>(w1, w2, w1b, w2b);
  router_kernel<<<2048, 256, 0, stream>>>(x, wr, probs);
  rank_kernel<<<dim3(4, 32), 256, 0, stream>>>(probs, gate_tok);
  ln_kernel<<<2048, 256, 0, stream>>>(x, gamma, beta, gate_tok, ytil, cntf, g4);
  fc1_kernel<<<2688, 256, 0, stream>>>(ytil, w1b, b1, cntf, y2b, qb, kb, vtb);
  attn_kernel<<<dim3(16, 96), 256, 0, stream>>>(qb, kb, vtb, y2b);
  fc2_kernel<<<768, 256, 0, stream>>>(y2b, w2b, b2, g4, x, out);
}

// Round 6
// 438.821 us; speedup vs baseline: 1.9634x; 1.1605x over previous
//
#include <hip/hip_runtime.h>
#include <math.h>

typedef __bf16 bf16_t;
typedef __bf16 bf16x8 __attribute__((ext_vector_type(8)));
typedef float f32x4 __attribute__((ext_vector_type(4)));

#define DIM 768
#define NE 4
#define NH 12
#define HD 64
#define MLP_HID 3072
#define FC1_OUT 5376
#define FC2_IN 3840
#define CAP 512
#define LOG2E 1.44269504088896340736f

__device__ __forceinline__ void async_copy16(const void* g, void* l) {
  __builtin_amdgcn_global_load_lds((const __attribute__((address_space(1))) void*)g,
                                   (__attribute__((address_space(3))) void*)l, 16, 0, 0);
}

// sigmoid-form tanh-GELU: gelu(v) = v * sigmoid(1.5958(v + 0.044715 v^3))
//  = v * rcp(1 + exp2(v*(c1 + c2*v^2))), c1=-2*log2e*0.7978846, c2=c1*0.044715
// max abs dev from exact-erf gelu ~7e-4 -- invisible at bf16.
__device__ __forceinline__ float gelu_f(float v) {
  float v2 = v * v;
  float t = v * fmaf(-0.102944f, v2, -2.302208f);
  float e = exp2f(t);
  return v * __builtin_amdgcn_rcpf(1.0f + e);
}

// ---------------- weight cast fp32 -> bf16 ----------------
__global__ __launch_bounds__(256) void cast_w_kernel(const float* __restrict__ w1,
                                                     const float* __restrict__ w2,
                                                     bf16_t* __restrict__ w1b,
                                                     bf16_t* __restrict__ w2b) {
  const int N1 = FC1_OUT * DIM;
  const int N2 = 1536 * FC2_IN;
  for (int i = blockIdx.x * 256 + threadIdx.x; i < N1 + N2; i += gridDim.x * 256) {
    if (i < N1) w1b[i] = (bf16_t)w1[i];
    else        w2b[i - N1] = (bf16_t)w2[i - N1];
  }
}

// ---------------- router: logits + softmax (fp32 exact; selection-critical) ----------------
__global__ __launch_bounds__(256) void router_kernel(const float* __restrict__ x,
                                                     const float* __restrict__ wr,
                                                     float* __restrict__ probs) {
  int t = blockIdx.x * 4 + (threadIdx.x >> 6);
  int l = threadIdx.x & 63;
  const float* xr = x + (size_t)t * DIM;
  float a0 = 0.f, a1 = 0.f, a2 = 0.f, a3 = 0.f;
#pragma unroll
  for (int i = 0; i < 12; i++) {
    int d = l + i * 64;
    float xv = xr[d];
    a0 += xv * wr[d];
    a1 += xv * wr[DIM + d];
    a2 += xv * wr[2 * DIM + d];
    a3 += xv * wr[3 * DIM + d];
  }
#pragma unroll
  for (int off = 32; off > 0; off >>= 1) {
    a0 += __shfl_down(a0, off);
    a1 += __shfl_down(a1, off);
    a2 += __shfl_down(a2, off);
    a3 += __shfl_down(a3, off);
  }
  if (l == 0) {
    float m = fmaxf(fmaxf(a0, a1), fmaxf(a2, a3));
    float e0 = expf(a0 - m), e1 = expf(a1 - m), e2 = expf(a2 - m), e3 = expf(a3 - m);
    float inv = 1.0f / (e0 + e1 + e2 + e3);
    int b = t >> 10, n = t & 1023;
    probs[(b * NE + 0) * 1024 + n] = e0 * inv;
    probs[(b * NE + 1) * 1024 + n] = e1 * inv;
    probs[(b * NE + 2) * 1024 + n] = e2 * inv;
    probs[(b * NE + 3) * 1024 + n] = e3 * inv;
  }
}

// ---------------- exact top-k membership via ranking ----------------
__global__ __launch_bounds__(256) void rank_kernel(const float* __restrict__ probs,
                                                   float* __restrict__ gate_tok) {
  int be = blockIdx.y;
  __shared__ float p[1024];
  for (int i = threadIdx.x; i < 1024; i += 256) p[i] = probs[be * 1024 + i];
  __syncthreads();
  int n = blockIdx.x * 256 + threadIdx.x;
  float pn = p[n];
  int rank = 0;
  for (int j = 0; j < 1024; j++) {
    float pj = p[j];
    rank += (pj > pn) || (pj == pn && j < n);
  }
  int b = be >> 2, e = be & 3;
  gate_tok[(size_t)((b << 10) + n) * 4 + e] = (rank < CAP) ? pn : 0.0f;
}

// ---------------- LayerNorm + segment-count scaling -> bf16; emit gate suffix sums ----------------
__global__ __launch_bounds__(256) void ln_kernel(const float* __restrict__ x,
                                                 const float* __restrict__ gamma,
                                                 const float* __restrict__ beta,
                                                 const float* __restrict__ gate_tok,
                                                 bf16_t* __restrict__ ytil,
                                                 float* __restrict__ cntf,
                                                 float* __restrict__ g4) {
  int t = blockIdx.x * 4 + (threadIdx.x >> 6);
  int l = threadIdx.x & 63;
  float4 gg = ((const float4*)gate_tok)[t];
  float s0 = (gg.x > 0.f) ? 1.f : 0.f;
  float s1 = (gg.y > 0.f) ? 1.f : 0.f;
  float s2 = (gg.z > 0.f) ? 1.f : 0.f;
  float s3 = (gg.w > 0.f) ? 1.f : 0.f;
  float c3 = s3, c2 = c3 + s2, c1 = c2 + s1, c0 = c1 + s0;
  if (l == 0) {
    cntf[t] = c0;
    float4 G;
    G.x = gg.x + gg.y + gg.z + gg.w;
    G.y = gg.y + gg.z + gg.w;
    G.z = gg.z + gg.w;
    G.w = gg.w;
    ((float4*)g4)[t] = G;
  }
  const float* xr = x + (size_t)t * DIM;
  float v[12];
  float s = 0.f, sq = 0.f;
#pragma unroll
  for (int i = 0; i < 12; i++) {
    v[i] = xr[l + i * 64];
    s += v[i];
    sq += v[i] * v[i];
  }
#pragma unroll
  for (int off = 1; off < 64; off <<= 1) {
    s += __shfl_xor(s, off);
    sq += __shfl_xor(sq, off);
  }
  float mean = s * (1.0f / DIM);
  float var = sq * (1.0f / DIM) - mean * mean;
  float rs = rsqrtf(var + 1e-6f);
#pragma unroll
  for (int i = 0; i < 12; i++) {
    int d = l + i * 64;
    float cf = (d < 96) ? c0 : (d < 192) ? c1 : (d < 384) ? c2 : c3;
    ytil[(size_t)t * DIM + d] = (bf16_t)(((v[i] - mean) * rs * gamma[d] + beta[d]) * cf);
  }
}

// ---------------- FC1 dense: [8192,5376] = ytil @ w1^T + cnt*b1; epilogue gelu / qkv split ----------------
// BK=64, XOR-swizzled async staging, nt-slow XCD order.
// __launch_bounds__(256,4): cap unified regs at 128 -> 4 blocks/CU (TLP hides the barrier chain).
__global__ __launch_bounds__(256, 4) void fc1_kernel(const bf16_t* __restrict__ ytil,
                                                     const bf16_t* __restrict__ w1b,
                                                     const float* __restrict__ b1,
                                                     const float* __restrict__ cntf,
                                                     bf16_t* __restrict__ y2b,
                                                     bf16_t* __restrict__ qb,
                                                     bf16_t* __restrict__ kb,
                                                     bf16_t* __restrict__ vtb) {
  const int bid = blockIdx.x;
  const int xcd = bid & 7, j = bid >> 3;      // j in 0..335
  const int mt = xcd * 8 + (j & 7);           // 0..63 (fast within XCD)
  const int nt = j >> 3;                      // 0..41 (slow)
  const int tid = threadIdx.x;
  const int w = tid >> 6, l = tid & 63;
  const int lq = l >> 4, lr = l & 15;

  __shared__ __align__(16) bf16_t lA[128 * 64];
  __shared__ __align__(16) bf16_t lB[128 * 64];

  f32x4 acc[4][4] = {};
  const int mwave = (w & 1) * 64, nwave = (w >> 1) * 64;
  const int crow = l >> 3;
  const int cbg = (l & 7) ^ (crow & 7);

  for (int k0 = 0; k0 < DIM; k0 += 64) {
#pragma unroll
    for (int i = 0; i < 4; i++) {
      int c = w * 4 + i;
      int row = c * 8 + crow;
      async_copy16(ytil + (size_t)(mt * 128 + row) * DIM + k0 + cbg * 8, lA + c * 512);
      async_copy16(w1b + (size_t)(nt * 128 + row) * DIM + k0 + cbg * 8, lB + c * 512);
    }
    __syncthreads();
#pragma unroll
    for (int ks = 0; ks < 2; ks++) {
      const int cbA = ((ks * 4 + lq) ^ (lr & 7)) * 8;
      bf16x8 af[4], bfr[4];
#pragma unroll
      for (int mi = 0; mi < 4; mi++)
        af[mi] = *(const bf16x8*)(lA + (mwave + mi * 16 + lr) * 64 + cbA);
#pragma unroll
      for (int ni = 0; ni < 4; ni++)
        bfr[ni] = *(const bf16x8*)(lB + (nwave + ni * 16 + lr) * 64 + cbA);
#pragma unroll
      for (int mi = 0; mi < 4; mi++)
#pragma unroll
        for (int ni = 0; ni < 4; ni++)
          acc[mi][ni] = __builtin_amdgcn_mfma_f32_16x16x32_bf16(af[mi], bfr[ni], acc[mi][ni], 0, 0, 0);
    }
    __syncthreads();
  }

#pragma unroll
  for (int mi = 0; mi < 4; mi++) {
    int row0 = mt * 128 + mwave + mi * 16 + lq * 4;
    float cnt[4];
#pragma unroll
    for (int r = 0; r < 4; r++) cnt[r] = cntf[row0 + r];
#pragma unroll
    for (int ni = 0; ni < 4; ni++) {
      int col = nt * 128 + nwave + ni * 16 + lr;
      float bias = b1[col];
      if (col < MLP_HID) {
#pragma unroll
        for (int r = 0; r < 4; r++) {
          float v = acc[mi][ni][r] + cnt[r] * bias;
          y2b[(size_t)(row0 + r) * FC2_IN + col] = (bf16_t)gelu_f(v);
        }
      } else {
        int part = col - MLP_HID;
        int comp = (part >= 1536) ? 2 : (part >= 768) ? 1 : 0;
        int rem = part - comp * 768;
        int hh = rem >> 6, d = rem & 63;
#pragma unroll
        for (int r = 0; r < 4; r++) {
          float v = acc[mi][ni][r] + cnt[r] * bias;
          int t = row0 + r;
          int b = t >> 10, n = t & 1023;
          size_t base = (size_t)(b * NH + hh);
          if (comp == 0)      qb[(base * 1024 + n) * HD + d] = (bf16_t)v;
          else if (comp == 1) kb[(base * 1024 + n) * HD + d] = (bf16_t)v;
          else                vtb[(base * HD + d) * 1024 + n] = (bf16_t)v;
        }
      }
    }
  }
}

// ---------------- flash attention (log2-domain online softmax), writes attn part of y2 ----------------
__global__ __launch_bounds__(256) void attn_kernel(const bf16_t* __restrict__ qb,
                                                   const bf16_t* __restrict__ kb,
                                                   const bf16_t* __restrict__ vtb,
                                                   bf16_t* __restrict__ y2b) {
  const int bh = blockIdx.y;
  const int qt = blockIdx.x;
  const int tid = threadIdx.x;
  const int w = tid >> 6, l = tid & 63, lq = l >> 4, lr = l & 15;

  __shared__ __align__(16) bf16_t lK[64 * 64];
  __shared__ __align__(16) bf16_t lV[64 * 64];
  __shared__ __align__(16) bf16_t lP[4][16 * 72];

  const bf16_t* qbase = qb + (size_t)bh * 1024 * HD;
  const bf16_t* kbase = kb + (size_t)bh * 1024 * HD;
  const bf16_t* vbase = vtb + (size_t)bh * HD * 1024;

  bf16x8 qf[2];
  int qrow = qt * 64 + w * 16 + lr;
#pragma unroll
  for (int s = 0; s < 2; s++)
    qf[s] = *(const bf16x8*)(qbase + (size_t)qrow * HD + s * 32 + lq * 8);

  f32x4 oacc[4] = {};
  float mrow[4], lrow[4];          // mrow in log2 units
#pragma unroll
  for (int r = 0; r < 4; r++) { mrow[r] = -1e30f; lrow[r] = 0.f; }

  const float s2 = 0.125f * LOG2E;
  const int crow = l >> 3;
  const int cbg = (l & 7) ^ (crow & 7);

  for (int kt = 0; kt < 16; kt++) {
#pragma unroll
    for (int i = 0; i < 2; i++) {
      int c = w * 2 + i;
      int row = c * 8 + crow;
      async_copy16(kbase + (size_t)(kt * 64 + row) * HD + cbg * 8, lK + c * 512);
      async_copy16(vbase + (size_t)row * 1024 + kt * 64 + cbg * 8, lV + c * 512);
    }
    __syncthreads();

    f32x4 sacc[4] = {};
#pragma unroll
    for (int s = 0; s < 2; s++) {
      const int cb = ((s * 4 + lq) ^ (lr & 7)) * 8;
#pragma unroll
      for (int kbq = 0; kbq < 4; kbq++) {
        bf16x8 kf = *(const bf16x8*)(lK + (kbq * 16 + lr) * 64 + cb);
        sacc[kbq] = __builtin_amdgcn_mfma_f32_16x16x32_bf16(qf[s], kf, sacc[kbq], 0, 0, 0);
      }
    }

    float sv[4][4];
    float tmax[4] = {-1e30f, -1e30f, -1e30f, -1e30f};
#pragma unroll
    for (int kbq = 0; kbq < 4; kbq++)
#pragma unroll
      for (int r = 0; r < 4; r++) {
        sv[kbq][r] = sacc[kbq][r] * s2;          // log2-domain score
        tmax[r] = fmaxf(tmax[r], sv[kbq][r]);
      }
#pragma unroll
    for (int off = 1; off < 16; off <<= 1)
#pragma unroll
      for (int r = 0; r < 4; r++) tmax[r] = fmaxf(tmax[r], __shfl_xor(tmax[r], off));

    float alpha[4], psum[4] = {0.f, 0.f, 0.f, 0.f};
#pragma unroll
    for (int r = 0; r < 4; r++) {
      float mnew = fmaxf(mrow[r], tmax[r]);
      alpha[r] = exp2f(mrow[r] - mnew);
      mrow[r] = mnew;
    }
    float pv[4][4];
#pragma unroll
    for (int kbq = 0; kbq < 4; kbq++)
#pragma unroll
      for (int r = 0; r < 4; r++) {
        pv[kbq][r] = exp2f(sv[kbq][r] - mrow[r]);
        psum[r] += pv[kbq][r];
      }
#pragma unroll
    for (int off = 1; off < 16; off <<= 1)
#pragma unroll
      for (int r = 0; r < 4; r++) psum[r] += __shfl_xor(psum[r], off);
#pragma unroll
    for (int r = 0; r < 4; r++) lrow[r] = lrow[r] * alpha[r] + psum[r];
#pragma unroll
    for (int nb = 0; nb < 4; nb++)
#pragma unroll
      for (int r = 0; r < 4; r++) oacc[nb][r] *= alpha[r];

    // P: C-layout -> wave-private LDS slab -> A-layout (no cross-wave barrier needed)
#pragma unroll
    for (int kbq = 0; kbq < 4; kbq++)
#pragma unroll
      for (int r = 0; r < 4; r++)
        lP[w][(lq * 4 + r) * 72 + kbq * 16 + lr] = (bf16_t)pv[kbq][r];

    bf16x8 pf[2];
#pragma unroll
    for (int s = 0; s < 2; s++)
      pf[s] = *(const bf16x8*)(&lP[w][lr * 72 + s * 32 + lq * 8]);

#pragma unroll
    for (int s = 0; s < 2; s++) {
      const int cb = ((s * 4 + lq) ^ (lr & 7)) * 8;
#pragma unroll
      for (int nb = 0; nb < 4; nb++) {
        bf16x8 vf = *(const bf16x8*)(lV + (nb * 16 + lr) * 64 + cb);
        oacc[nb] = __builtin_amdgcn_mfma_f32_16x16x32_bf16(pf[s], vf, oacc[nb], 0, 0, 0);
      }
    }
    __syncthreads();
  }

  int b = bh / NH, hh = bh % NH;
#pragma unroll
  for (int nb = 0; nb < 4; nb++)
#pragma unroll
    for (int r = 0; r < 4; r++) {
      float v = oacc[nb][r] / lrow[r];
      int tok = qt * 64 + w * 16 + lq * 4 + r;
      y2b[((size_t)(b * 1024 + tok)) * FC2_IN + MLP_HID + hh * HD + nb * 16 + lr] = (bf16_t)v;
    }
}

// ---------------- FC2 dense fused: out = x + Sum_halves G_seg(col) * (y2 @ w2^T + b2) ----------------
__global__ __launch_bounds__(256, 4) void fc2_kernel(const bf16_t* __restrict__ y2b,
                                                     const bf16_t* __restrict__ w2b,
                                                     const float* __restrict__ b2,
                                                     const float* __restrict__ g4,
                                                     const float* __restrict__ x,
                                                     float* __restrict__ out) {
  const int bid = blockIdx.x;
  const int xcd = bid & 7, j = bid >> 3;
  const int mt = xcd * 8 + j / 12;
  const int ct = j % 12;
  const int tid = threadIdx.x;
  const int w = tid >> 6, l = tid & 63;
  const int lq = l >> 4, lr = l & 15;

  __shared__ __align__(16) bf16_t lA[128 * 64];
  __shared__ __align__(16) bf16_t lB[128 * 64];

  f32x4 acc[2][4][2] = {};
  const int mwave = (w & 1) * 64, nwave = (w >> 1) * 32;
  const int crow = l >> 3;
  const int cbg = (l & 7) ^ (crow & 7);

  for (int k0 = 0; k0 < FC2_IN; k0 += 64) {
#pragma unroll
    for (int i = 0; i < 4; i++) {
      int c = w * 4 + i;
      int row = c * 8 + crow;
      async_copy16(y2b + (size_t)(mt * 128 + row) * FC2_IN + k0 + cbg * 8, lA + c * 512);
      int grow = ((row >> 6) * 768) + ct * 64 + (row & 63);
      async_copy16(w2b + (size_t)grow * FC2_IN + k0 + cbg * 8, lB + c * 512);
    }
    __syncthreads();
#pragma unroll
    for (int ks = 0; ks < 2; ks++) {
      const int cbA = ((ks * 4 + lq) ^ (lr & 7)) * 8;
      bf16x8 af[4], bfr[2][2];
#pragma unroll
      for (int mi = 0; mi < 4; mi++)
        af[mi] = *(const bf16x8*)(lA + (mwave + mi * 16 + lr) * 64 + cbA);
#pragma unroll
      for (int h = 0; h < 2; h++)
#pragma unroll
        for (int ni = 0; ni < 2; ni++)
          bfr[h][ni] = *(const bf16x8*)(lB + (h * 64 + nwave + ni * 16 + lr) * 64 + cbA);
#pragma unroll
      for (int h = 0; h < 2; h++)
#pragma unroll
        for (int mi = 0; mi < 4; mi++)
#pragma unroll
          for (int ni = 0; ni < 2; ni++)
            acc[h][mi][ni] = __builtin_amdgcn_mfma_f32_16x16x32_bf16(af[mi], bfr[h][ni], acc[h][mi][ni], 0, 0, 0);
    }
    __syncthreads();
  }

#pragma unroll
  for (int mi = 0; mi < 4; mi++) {
    int row0 = mt * 128 + mwave + mi * 16 + lq * 4;
    float4 G[4];
#pragma unroll
    for (int r = 0; r < 4; r++) G[r] = ((const float4*)g4)[row0 + r];
#pragma unroll
    for (int ni = 0; ni < 2; ni++) {
      int col = ct * 64 + nwave + ni * 16 + lr;
      float b20 = b2[col], b21 = b2[768 + col];
#pragma unroll
      for (int r = 0; r < 4; r++) {
        float gw = (col < 96) ? G[r].x : (col < 192) ? G[r].y : (col < 384) ? G[r].z : G[r].w;
        float o = (acc[0][mi][ni][r] + b20) + (acc[1][mi][ni][r] + b21);
        size_t idx = (size_t)(row0 + r) * DIM + col;
        out[idx] = x[idx] + gw * o;
      }
    }
  }
}

extern "C" void kernel_launch(void* const* d_in, const int* in_sizes, int n_in,
                              void* d_out, int out_size, void* d_ws, size_t ws_size,
                              hipStream_t stream) {
  const float* x     = (const float*)d_in[0];
  const float* wr    = (const float*)d_in[1];
  const float* gamma = (const float*)d_in[2];
  const float* beta  = (const float*)d_in[3];
  const float* w1    = (const float*)d_in[4];
  const float* b1    = (const float*)d_in[5];
  const float* w2    = (const float*)d_in[6];
  const float* b2    = (const float*)d_in[7];
  float* out = (float*)d_out;

  char* ws = (char*)d_ws;
  float*  probs    = (float*)(ws + 0);            // 131072
  float*  gate_tok = (float*)(ws + 131072);       // 131072
  float*  cntf     = (float*)(ws + 262144);       // 32768
  float*  g4       = (float*)(ws + 294912);       // 131072
  bf16_t* w1b      = (bf16_t*)(ws + 425984);      // 8257536
  bf16_t* w2b      = (bf16_t*)(ws + 8683520);     // 11796480
  bf16_t* ytil     = (bf16_t*)(ws + 20480000);    // 12582912
  bf16_t* y2b      = (bf16_t*)(ws + 33062912);    // 62914560
  bf16_t* qb       = (bf16_t*)(ws + 95977472);    // 12582912
  bf16_t* kb       = (bf16_t*)(ws + 108560384);   // 12582912
  bf16_t* vtb      = (bf16_t*)(ws + 121143296);   // 12582912

  cast_w_kernel<<<2048, 256, 0, stream>>>(w1, w2, w1b, w2b);
  router_kernel<<<2048, 256, 0, stream>>>(x, wr, probs);
  rank_kernel<<<dim3(4, 32), 256, 0, stream>>>(probs, gate_tok);
  ln_kernel<<<2048, 256, 0, stream>>>(x, gamma, beta, gate_tok, ytil, cntf, g4);
  fc1_kernel<<<2688, 256, 0, stream>>>(ytil, w1b, b1, cntf, y2b, qb, kb, vtb);
  attn_kernel<<<dim3(16, 96), 256, 0, stream>>>(qb, kb, vtb, y2b);
  fc2_kernel<<<768, 256, 0, stream>>>(y2b, w2b, b2, g4, x, out);
}

// Round 7
// 391.024 us; speedup vs baseline: 2.2034x; 1.1222x over previous
//
#include <hip/hip_runtime.h>
#include <math.h>

typedef __bf16 bf16_t;
typedef __bf16 bf16x8 __attribute__((ext_vector_type(8)));
typedef float f32x4 __attribute__((ext_vector_type(4)));

#define DIM 768
#define NE 4
#define NH 12
#define HD 64
#define MLP_HID 3072
#define FC1_OUT 5376
#define FC2_IN 3840
#define CAP 512
#define LOG2E 1.44269504088896340736f

__device__ __forceinline__ void async_copy16(const void* g, void* l) {
  __builtin_amdgcn_global_load_lds((const __attribute__((address_space(1))) void*)g,
                                   (__attribute__((address_space(3))) void*)l, 16, 0, 0);
}

// sigmoid-form tanh-GELU: gelu(v) = v * rcp(1 + exp2(v*(c1 + c2*v^2)))
// max abs dev from exact-erf gelu ~7e-4 -- invisible at bf16.
__device__ __forceinline__ float gelu_f(float v) {
  float v2 = v * v;
  float t = v * fmaf(-0.102944f, v2, -2.302208f);
  float e = exp2f(t);
  return v * __builtin_amdgcn_rcpf(1.0f + e);
}

// ---------------- weight cast fp32 -> bf16 ----------------
__global__ __launch_bounds__(256) void cast_w_kernel(const float* __restrict__ w1,
                                                     const float* __restrict__ w2,
                                                     bf16_t* __restrict__ w1b,
                                                     bf16_t* __restrict__ w2b) {
  const int N1 = FC1_OUT * DIM;
  const int N2 = 1536 * FC2_IN;
  for (int i = blockIdx.x * 256 + threadIdx.x; i < N1 + N2; i += gridDim.x * 256) {
    if (i < N1) w1b[i] = (bf16_t)w1[i];
    else        w2b[i - N1] = (bf16_t)w2[i - N1];
  }
}

// ---------------- router: logits + softmax (fp32 exact; selection-critical) ----------------
__global__ __launch_bounds__(256) void router_kernel(const float* __restrict__ x,
                                                     const float* __restrict__ wr,
                                                     float* __restrict__ probs) {
  int t = blockIdx.x * 4 + (threadIdx.x >> 6);
  int l = threadIdx.x & 63;
  const float* xr = x + (size_t)t * DIM;
  float a0 = 0.f, a1 = 0.f, a2 = 0.f, a3 = 0.f;
#pragma unroll
  for (int i = 0; i < 12; i++) {
    int d = l + i * 64;
    float xv = xr[d];
    a0 += xv * wr[d];
    a1 += xv * wr[DIM + d];
    a2 += xv * wr[2 * DIM + d];
    a3 += xv * wr[3 * DIM + d];
  }
#pragma unroll
  for (int off = 32; off > 0; off >>= 1) {
    a0 += __shfl_down(a0, off);
    a1 += __shfl_down(a1, off);
    a2 += __shfl_down(a2, off);
    a3 += __shfl_down(a3, off);
  }
  if (l == 0) {
    float m = fmaxf(fmaxf(a0, a1), fmaxf(a2, a3));
    float e0 = expf(a0 - m), e1 = expf(a1 - m), e2 = expf(a2 - m), e3 = expf(a3 - m);
    float inv = 1.0f / (e0 + e1 + e2 + e3);
    int b = t >> 10, n = t & 1023;
    probs[(b * NE + 0) * 1024 + n] = e0 * inv;
    probs[(b * NE + 1) * 1024 + n] = e1 * inv;
    probs[(b * NE + 2) * 1024 + n] = e2 * inv;
    probs[(b * NE + 3) * 1024 + n] = e3 * inv;
  }
}

// ---------------- exact top-k membership via ranking ----------------
__global__ __launch_bounds__(256) void rank_kernel(const float* __restrict__ probs,
                                                   float* __restrict__ gate_tok) {
  int be = blockIdx.y;
  __shared__ float p[1024];
  for (int i = threadIdx.x; i < 1024; i += 256) p[i] = probs[be * 1024 + i];
  __syncthreads();
  int n = blockIdx.x * 256 + threadIdx.x;
  float pn = p[n];
  int rank = 0;
  for (int j = 0; j < 1024; j++) {
    float pj = p[j];
    rank += (pj > pn) || (pj == pn && j < n);
  }
  int b = be >> 2, e = be & 3;
  gate_tok[(size_t)((b << 10) + n) * 4 + e] = (rank < CAP) ? pn : 0.0f;
}

// ---------------- LayerNorm + segment-count scaling -> bf16; emit gate suffix sums ----------------
__global__ __launch_bounds__(256) void ln_kernel(const float* __restrict__ x,
                                                 const float* __restrict__ gamma,
                                                 const float* __restrict__ beta,
                                                 const float* __restrict__ gate_tok,
                                                 bf16_t* __restrict__ ytil,
                                                 float* __restrict__ cntf,
                                                 float* __restrict__ g4) {
  int t = blockIdx.x * 4 + (threadIdx.x >> 6);
  int l = threadIdx.x & 63;
  float4 gg = ((const float4*)gate_tok)[t];
  float s0 = (gg.x > 0.f) ? 1.f : 0.f;
  float s1 = (gg.y > 0.f) ? 1.f : 0.f;
  float s2 = (gg.z > 0.f) ? 1.f : 0.f;
  float s3 = (gg.w > 0.f) ? 1.f : 0.f;
  float c3 = s3, c2 = c3 + s2, c1 = c2 + s1, c0 = c1 + s0;
  if (l == 0) {
    cntf[t] = c0;
    float4 G;
    G.x = gg.x + gg.y + gg.z + gg.w;
    G.y = gg.y + gg.z + gg.w;
    G.z = gg.z + gg.w;
    G.w = gg.w;
    ((float4*)g4)[t] = G;
  }
  const float* xr = x + (size_t)t * DIM;
  float v[12];
  float s = 0.f, sq = 0.f;
#pragma unroll
  for (int i = 0; i < 12; i++) {
    v[i] = xr[l + i * 64];
    s += v[i];
    sq += v[i] * v[i];
  }
#pragma unroll
  for (int off = 1; off < 64; off <<= 1) {
    s += __shfl_xor(s, off);
    sq += __shfl_xor(sq, off);
  }
  float mean = s * (1.0f / DIM);
  float var = sq * (1.0f / DIM) - mean * mean;
  float rs = rsqrtf(var + 1e-6f);
#pragma unroll
  for (int i = 0; i < 12; i++) {
    int d = l + i * 64;
    float cf = (d < 96) ? c0 : (d < 192) ? c1 : (d < 384) ? c2 : c3;
    ytil[(size_t)t * DIM + d] = (bf16_t)(((v[i] - mean) * rs * gamma[d] + beta[d]) * cf);
  }
}

// ---------------- FC1 dense: [8192,5376] = ytil @ w1^T + cnt*b1; epilogue gelu / qkv split ----------------
// Q is pre-scaled by 0.125*log2e so attention scores are directly in log2 units.
__global__ __launch_bounds__(256, 4) void fc1_kernel(const bf16_t* __restrict__ ytil,
                                                     const bf16_t* __restrict__ w1b,
                                                     const float* __restrict__ b1,
                                                     const float* __restrict__ cntf,
                                                     bf16_t* __restrict__ y2b,
                                                     bf16_t* __restrict__ qb,
                                                     bf16_t* __restrict__ kb,
                                                     bf16_t* __restrict__ vtb) {
  const int bid = blockIdx.x;
  const int xcd = bid & 7, j = bid >> 3;      // j in 0..335
  const int mt = xcd * 8 + (j & 7);           // 0..63 (fast within XCD)
  const int nt = j >> 3;                      // 0..41 (slow)
  const int tid = threadIdx.x;
  const int w = tid >> 6, l = tid & 63;
  const int lq = l >> 4, lr = l & 15;

  __shared__ __align__(16) bf16_t lA[128 * 64];
  __shared__ __align__(16) bf16_t lB[128 * 64];

  f32x4 acc[4][4] = {};
  const int mwave = (w & 1) * 64, nwave = (w >> 1) * 64;
  const int crow = l >> 3;
  const int cbg = (l & 7) ^ (crow & 7);

  for (int k0 = 0; k0 < DIM; k0 += 64) {
#pragma unroll
    for (int i = 0; i < 4; i++) {
      int c = w * 4 + i;
      int row = c * 8 + crow;
      async_copy16(ytil + (size_t)(mt * 128 + row) * DIM + k0 + cbg * 8, lA + c * 512);
      async_copy16(w1b + (size_t)(nt * 128 + row) * DIM + k0 + cbg * 8, lB + c * 512);
    }
    __syncthreads();
#pragma unroll
    for (int ks = 0; ks < 2; ks++) {
      const int cbA = ((ks * 4 + lq) ^ (lr & 7)) * 8;
      bf16x8 af[4], bfr[4];
#pragma unroll
      for (int mi = 0; mi < 4; mi++)
        af[mi] = *(const bf16x8*)(lA + (mwave + mi * 16 + lr) * 64 + cbA);
#pragma unroll
      for (int ni = 0; ni < 4; ni++)
        bfr[ni] = *(const bf16x8*)(lB + (nwave + ni * 16 + lr) * 64 + cbA);
#pragma unroll
      for (int mi = 0; mi < 4; mi++)
#pragma unroll
        for (int ni = 0; ni < 4; ni++)
          acc[mi][ni] = __builtin_amdgcn_mfma_f32_16x16x32_bf16(af[mi], bfr[ni], acc[mi][ni], 0, 0, 0);
    }
    __syncthreads();
  }

#pragma unroll
  for (int mi = 0; mi < 4; mi++) {
    int row0 = mt * 128 + mwave + mi * 16 + lq * 4;
    float cnt[4];
#pragma unroll
    for (int r = 0; r < 4; r++) cnt[r] = cntf[row0 + r];
#pragma unroll
    for (int ni = 0; ni < 4; ni++) {
      int col = nt * 128 + nwave + ni * 16 + lr;
      float bias = b1[col];
      if (col < MLP_HID) {
#pragma unroll
        for (int r = 0; r < 4; r++) {
          float v = acc[mi][ni][r] + cnt[r] * bias;
          y2b[(size_t)(row0 + r) * FC2_IN + col] = (bf16_t)gelu_f(v);
        }
      } else {
        int part = col - MLP_HID;
        int comp = (part >= 1536) ? 2 : (part >= 768) ? 1 : 0;
        int rem = part - comp * 768;
        int hh = rem >> 6, d = rem & 63;
#pragma unroll
        for (int r = 0; r < 4; r++) {
          float v = acc[mi][ni][r] + cnt[r] * bias;
          int t = row0 + r;
          int b = t >> 10, n = t & 1023;
          size_t base = (size_t)(b * NH + hh);
          if (comp == 0)      qb[(base * 1024 + n) * HD + d] = (bf16_t)(v * (0.125f * LOG2E));
          else if (comp == 1) kb[(base * 1024 + n) * HD + d] = (bf16_t)v;
          else                vtb[(base * HD + d) * 1024 + n] = (bf16_t)v;
        }
      }
    }
  }
}

// ---------------- flash attention, no-max softmax (scores bounded), writes attn part of y2 ----------------
// Q pre-scaled: sacc is directly log2-domain. No running max, no alpha, no per-iter trees:
// per-lane psum accumulated across all kt tiles, single cross-lane reduction at the end.
__global__ __launch_bounds__(256) void attn_kernel(const bf16_t* __restrict__ qb,
                                                   const bf16_t* __restrict__ kb,
                                                   const bf16_t* __restrict__ vtb,
                                                   bf16_t* __restrict__ y2b) {
  const int bh = blockIdx.y;
  const int qt = blockIdx.x;
  const int tid = threadIdx.x;
  const int w = tid >> 6, l = tid & 63, lq = l >> 4, lr = l & 15;

  __shared__ __align__(16) bf16_t lK[64 * 64];
  __shared__ __align__(16) bf16_t lV[64 * 64];
  __shared__ __align__(16) bf16_t lP[4][16 * 72];

  const bf16_t* qbase = qb + (size_t)bh * 1024 * HD;
  const bf16_t* kbase = kb + (size_t)bh * 1024 * HD;
  const bf16_t* vbase = vtb + (size_t)bh * HD * 1024;

  bf16x8 qf[2];
  int qrow = qt * 64 + w * 16 + lr;
#pragma unroll
  for (int s = 0; s < 2; s++)
    qf[s] = *(const bf16x8*)(qbase + (size_t)qrow * HD + s * 32 + lq * 8);

  f32x4 oacc[4] = {};
  float psum[4] = {0.f, 0.f, 0.f, 0.f};

  const int crow = l >> 3;
  const int cbg = (l & 7) ^ (crow & 7);

  for (int kt = 0; kt < 16; kt++) {
#pragma unroll
    for (int i = 0; i < 2; i++) {
      int c = w * 2 + i;
      int row = c * 8 + crow;
      async_copy16(kbase + (size_t)(kt * 64 + row) * HD + cbg * 8, lK + c * 512);
      async_copy16(vbase + (size_t)row * 1024 + kt * 64 + cbg * 8, lV + c * 512);
    }
    __syncthreads();

    f32x4 sacc[4] = {};
#pragma unroll
    for (int s = 0; s < 2; s++) {
      const int cb = ((s * 4 + lq) ^ (lr & 7)) * 8;
#pragma unroll
      for (int kbq = 0; kbq < 4; kbq++) {
        bf16x8 kf = *(const bf16x8*)(lK + (kbq * 16 + lr) * 64 + cb);
        sacc[kbq] = __builtin_amdgcn_mfma_f32_16x16x32_bf16(qf[s], kf, sacc[kbq], 0, 0, 0);
      }
    }

    // pv = exp2(score); accumulate per-lane partial row sums (cols lr mod 16)
#pragma unroll
    for (int kbq = 0; kbq < 4; kbq++)
#pragma unroll
      for (int r = 0; r < 4; r++) {
        float pv = exp2f(sacc[kbq][r]);
        psum[r] += pv;
        lP[w][(lq * 4 + r) * 72 + kbq * 16 + lr] = (bf16_t)pv;
      }

    bf16x8 pf[2];
#pragma unroll
    for (int s = 0; s < 2; s++)
      pf[s] = *(const bf16x8*)(&lP[w][lr * 72 + s * 32 + lq * 8]);

#pragma unroll
    for (int s = 0; s < 2; s++) {
      const int cb = ((s * 4 + lq) ^ (lr & 7)) * 8;
#pragma unroll
      for (int nb = 0; nb < 4; nb++) {
        bf16x8 vf = *(const bf16x8*)(lV + (nb * 16 + lr) * 64 + cb);
        oacc[nb] = __builtin_amdgcn_mfma_f32_16x16x32_bf16(pf[s], vf, oacc[nb], 0, 0, 0);
      }
    }
    __syncthreads();
  }

  // one cross-lane reduction for the full row sums (within each 16-lane lr group)
#pragma unroll
  for (int off = 1; off < 16; off <<= 1)
#pragma unroll
    for (int r = 0; r < 4; r++) psum[r] += __shfl_xor(psum[r], off);
  float rinv[4];
#pragma unroll
  for (int r = 0; r < 4; r++) rinv[r] = 1.0f / psum[r];

  int b = bh / NH, hh = bh % NH;
#pragma unroll
  for (int nb = 0; nb < 4; nb++)
#pragma unroll
    for (int r = 0; r < 4; r++) {
      float v = oacc[nb][r] * rinv[r];
      int tok = qt * 64 + w * 16 + lq * 4 + r;
      y2b[((size_t)(b * 1024 + tok)) * FC2_IN + MLP_HID + hh * HD + nb * 16 + lr] = (bf16_t)v;
    }
}

// ---------------- FC2 dense fused: out = x + Sum_halves G_seg(col) * (y2 @ w2^T + b2) ----------------
__global__ __launch_bounds__(256, 4) void fc2_kernel(const bf16_t* __restrict__ y2b,
                                                     const bf16_t* __restrict__ w2b,
                                                     const float* __restrict__ b2,
                                                     const float* __restrict__ g4,
                                                     const float* __restrict__ x,
                                                     float* __restrict__ out) {
  const int bid = blockIdx.x;
  const int xcd = bid & 7, j = bid >> 3;
  const int mt = xcd * 8 + j / 12;
  const int ct = j % 12;
  const int tid = threadIdx.x;
  const int w = tid >> 6, l = tid & 63;
  const int lq = l >> 4, lr = l & 15;

  __shared__ __align__(16) bf16_t lA[128 * 64];
  __shared__ __align__(16) bf16_t lB[128 * 64];

  f32x4 acc[2][4][2] = {};
  const int mwave = (w & 1) * 64, nwave = (w >> 1) * 32;
  const int crow = l >> 3;
  const int cbg = (l & 7) ^ (crow & 7);

  for (int k0 = 0; k0 < FC2_IN; k0 += 64) {
#pragma unroll
    for (int i = 0; i < 4; i++) {
      int c = w * 4 + i;
      int row = c * 8 + crow;
      async_copy16(y2b + (size_t)(mt * 128 + row) * FC2_IN + k0 + cbg * 8, lA + c * 512);
      int grow = ((row >> 6) * 768) + ct * 64 + (row & 63);
      async_copy16(w2b + (size_t)grow * FC2_IN + k0 + cbg * 8, lB + c * 512);
    }
    __syncthreads();
#pragma unroll
    for (int ks = 0; ks < 2; ks++) {
      const int cbA = ((ks * 4 + lq) ^ (lr & 7)) * 8;
      bf16x8 af[4], bfr[2][2];
#pragma unroll
      for (int mi = 0; mi < 4; mi++)
        af[mi] = *(const bf16x8*)(lA + (mwave + mi * 16 + lr) * 64 + cbA);
#pragma unroll
      for (int h = 0; h < 2; h++)
#pragma unroll
        for (int ni = 0; ni < 2; ni++)
          bfr[h][ni] = *(const bf16x8*)(lB + (h * 64 + nwave + ni * 16 + lr) * 64 + cbA);
#pragma unroll
      for (int h = 0; h < 2; h++)
#pragma unroll
        for (int mi = 0; mi < 4; mi++)
#pragma unroll
          for (int ni = 0; ni < 2; ni++)
            acc[h][mi][ni] = __builtin_amdgcn_mfma_f32_16x16x32_bf16(af[mi], bfr[h][ni], acc[h][mi][ni], 0, 0, 0);
    }
    __syncthreads();
  }

#pragma unroll
  for (int mi = 0; mi < 4; mi++) {
    int row0 = mt * 128 + mwave + mi * 16 + lq * 4;
    float4 G[4];
#pragma unroll
    for (int r = 0; r < 4; r++) G[r] = ((const float4*)g4)[row0 + r];
#pragma unroll
    for (int ni = 0; ni < 2; ni++) {
      int col = ct * 64 + nwave + ni * 16 + lr;
      float b20 = b2[col], b21 = b2[768 + col];
#pragma unroll
      for (int r = 0; r < 4; r++) {
        float gw = (col < 96) ? G[r].x : (col < 192) ? G[r].y : (col < 384) ? G[r].z : G[r].w;
        float o = (acc[0][mi][ni][r] + b20) + (acc[1][mi][ni][r] + b21);
        size_t idx = (size_t)(row0 + r) * DIM + col;
        out[idx] = x[idx] + gw * o;
      }
    }
  }
}

extern "C" void kernel_launch(void* const* d_in, const int* in_sizes, int n_in,
                              void* d_out, int out_size, void* d_ws, size_t ws_size,
                              hipStream_t stream) {
  const float* x     = (const float*)d_in[0];
  const float* wr    = (const float*)d_in[1];
  const float* gamma = (const float*)d_in[2];
  const float* beta  = (const float*)d_in[3];
  const float* w1    = (const float*)d_in[4];
  const float* b1    = (const float*)d_in[5];
  const float* w2    = (const float*)d_in[6];
  const float* b2    = (const float*)d_in[7];
  float* out = (float*)d_out;

  char* ws = (char*)d_ws;
  float*  probs    = (float*)(ws + 0);            // 131072
  float*  gate_tok = (float*)(ws + 131072);       // 131072
  float*  cntf     = (float*)(ws + 262144);       // 32768
  float*  g4       = (float*)(ws + 294912);       // 131072
  bf16_t* w1b      = (bf16_t*)(ws + 425984);      // 8257536
  bf16_t* w2b      = (bf16_t*)(ws + 8683520);     // 11796480
  bf16_t* ytil     = (bf16_t*)(ws + 20480000);    // 12582912
  bf16_t* y2b      = (bf16_t*)(ws + 33062912);    // 62914560
  bf16_t* qb       = (bf16_t*)(ws + 95977472);    // 12582912
  bf16_t* kb       = (bf16_t*)(ws + 108560384);   // 12582912
  bf16_t* vtb      = (bf16_t*)(ws + 121143296);   // 12582912

  cast_w_kernel<<<2048, 256, 0, stream>>>(w1, w2, w1b, w2b);
  router_kernel<<<2048, 256, 0, stream>>>(x, wr, probs);
  rank_kernel<<<dim3(4, 32), 256, 0, stream>>>(probs, gate_tok);
  ln_kernel<<<2048, 256, 0, stream>>>(x, gamma, beta, gate_tok, ytil, cntf, g4);
  fc1_kernel<<<2688, 256, 0, stream>>>(ytil, w1b, b1, cntf, y2b, qb, kb, vtb);
  attn_kernel<<<dim3(16, 96), 256, 0, stream>>>(qb, kb, vtb, y2b);
  fc2_kernel<<<768, 256, 0, stream>>>(y2b, w2b, b2, g4, x, out);
}

// Round 8
// 379.603 us; speedup vs baseline: 2.2697x; 1.0301x over previous
//
#include <hip/hip_runtime.h>
#include <math.h>

typedef __bf16 bf16_t;
typedef __bf16 bf16x8 __attribute__((ext_vector_type(8)));
typedef __bf16 bf16x4 __attribute__((ext_vector_type(4)));
typedef float f32x4 __attribute__((ext_vector_type(4)));

#define DIM 768
#define NE 4
#define NH 12
#define HD 64
#define MLP_HID 3072
#define FC1_OUT 5376
#define FC2_IN 3840
#define CAP 512
#define LOG2E 1.44269504088896340736f

__device__ __forceinline__ void async_copy16(const void* g, void* l) {
  __builtin_amdgcn_global_load_lds((const __attribute__((address_space(1))) void*)g,
                                   (__attribute__((address_space(3))) void*)l, 16, 0, 0);
}

// sigmoid-form tanh-GELU: gelu(v) = v * rcp(1 + exp2(v*(c1 + c2*v^2)))
// max abs dev from exact-erf gelu ~7e-4 -- invisible at bf16.
__device__ __forceinline__ float gelu_f(float v) {
  float v2 = v * v;
  float t = v * fmaf(-0.102944f, v2, -2.302208f);
  float e = exp2f(t);
  return v * __builtin_amdgcn_rcpf(1.0f + e);
}

// ---------------- fused: weight cast (blocks 0..2047) + router softmax (blocks 2048..4095) ----------------
__global__ __launch_bounds__(256) void cast_router_kernel(const float* __restrict__ w1,
                                                          const float* __restrict__ w2,
                                                          bf16_t* __restrict__ w1b,
                                                          bf16_t* __restrict__ w2b,
                                                          const float* __restrict__ x,
                                                          const float* __restrict__ wr,
                                                          float* __restrict__ probs) {
  if (blockIdx.x < 2048) {
    const int N1 = FC1_OUT * DIM;
    const int N2 = 1536 * FC2_IN;
    for (int i = blockIdx.x * 256 + threadIdx.x; i < N1 + N2; i += 2048 * 256) {
      if (i < N1) w1b[i] = (bf16_t)w1[i];
      else        w2b[i - N1] = (bf16_t)w2[i - N1];
    }
    return;
  }
  int t = (blockIdx.x - 2048) * 4 + (threadIdx.x >> 6);
  int l = threadIdx.x & 63;
  const float* xr = x + (size_t)t * DIM;
  float a0 = 0.f, a1 = 0.f, a2 = 0.f, a3 = 0.f;
#pragma unroll
  for (int i = 0; i < 12; i++) {
    int d = l + i * 64;
    float xv = xr[d];
    a0 += xv * wr[d];
    a1 += xv * wr[DIM + d];
    a2 += xv * wr[2 * DIM + d];
    a3 += xv * wr[3 * DIM + d];
  }
#pragma unroll
  for (int off = 32; off > 0; off >>= 1) {
    a0 += __shfl_down(a0, off);
    a1 += __shfl_down(a1, off);
    a2 += __shfl_down(a2, off);
    a3 += __shfl_down(a3, off);
  }
  if (l == 0) {
    float m = fmaxf(fmaxf(a0, a1), fmaxf(a2, a3));
    float e0 = expf(a0 - m), e1 = expf(a1 - m), e2 = expf(a2 - m), e3 = expf(a3 - m);
    float inv = 1.0f / (e0 + e1 + e2 + e3);
    int b = t >> 10, n = t & 1023;
    probs[(b * NE + 0) * 1024 + n] = e0 * inv;
    probs[(b * NE + 1) * 1024 + n] = e1 * inv;
    probs[(b * NE + 2) * 1024 + n] = e2 * inv;
    probs[(b * NE + 3) * 1024 + n] = e3 * inv;
  }
}

// ---------------- exact top-k membership via ranking ----------------
__global__ __launch_bounds__(256) void rank_kernel(const float* __restrict__ probs,
                                                   float* __restrict__ gate_tok) {
  int be = blockIdx.y;
  __shared__ float p[1024];
  for (int i = threadIdx.x; i < 1024; i += 256) p[i] = probs[be * 1024 + i];
  __syncthreads();
  int n = blockIdx.x * 256 + threadIdx.x;
  float pn = p[n];
  int rank = 0;
  for (int j = 0; j < 1024; j++) {
    float pj = p[j];
    rank += (pj > pn) || (pj == pn && j < n);
  }
  int b = be >> 2, e = be & 3;
  gate_tok[(size_t)((b << 10) + n) * 4 + e] = (rank < CAP) ? pn : 0.0f;
}

// ---------------- LayerNorm + segment-count scaling -> bf16; emit gate suffix sums ----------------
__global__ __launch_bounds__(256) void ln_kernel(const float* __restrict__ x,
                                                 const float* __restrict__ gamma,
                                                 const float* __restrict__ beta,
                                                 const float* __restrict__ gate_tok,
                                                 bf16_t* __restrict__ ytil,
                                                 float* __restrict__ cntf,
                                                 float* __restrict__ g4) {
  int t = blockIdx.x * 4 + (threadIdx.x >> 6);
  int l = threadIdx.x & 63;
  float4 gg = ((const float4*)gate_tok)[t];
  float s0 = (gg.x > 0.f) ? 1.f : 0.f;
  float s1 = (gg.y > 0.f) ? 1.f : 0.f;
  float s2 = (gg.z > 0.f) ? 1.f : 0.f;
  float s3 = (gg.w > 0.f) ? 1.f : 0.f;
  float c3 = s3, c2 = c3 + s2, c1 = c2 + s1, c0 = c1 + s0;
  if (l == 0) {
    cntf[t] = c0;
    float4 G;
    G.x = gg.x + gg.y + gg.z + gg.w;
    G.y = gg.y + gg.z + gg.w;
    G.z = gg.z + gg.w;
    G.w = gg.w;
    ((float4*)g4)[t] = G;
  }
  const float* xr = x + (size_t)t * DIM;
  float v[12];
  float s = 0.f, sq = 0.f;
#pragma unroll
  for (int i = 0; i < 12; i++) {
    v[i] = xr[l + i * 64];
    s += v[i];
    sq += v[i] * v[i];
  }
#pragma unroll
  for (int off = 1; off < 64; off <<= 1) {
    s += __shfl_xor(s, off);
    sq += __shfl_xor(sq, off);
  }
  float mean = s * (1.0f / DIM);
  float var = sq * (1.0f / DIM) - mean * mean;
  float rs = rsqrtf(var + 1e-6f);
#pragma unroll
  for (int i = 0; i < 12; i++) {
    int d = l + i * 64;
    float cf = (d < 96) ? c0 : (d < 192) ? c1 : (d < 384) ? c2 : c3;
    ytil[(size_t)t * DIM + d] = (bf16_t)(((v[i] - mean) * rs * gamma[d] + beta[d]) * cf);
  }
}

// ---------------- FC1 dense: [8192,5376] = ytil @ w1^T + cnt*b1; epilogue gelu / qkv split ----------------
// Q is pre-scaled by 0.125*log2e so attention scores are directly in log2 units.
// vtb (transposed V) stores packed 4x bf16 across r (n consecutive) -> 4x fewer scattered stores.
__global__ __launch_bounds__(256, 4) void fc1_kernel(const bf16_t* __restrict__ ytil,
                                                     const bf16_t* __restrict__ w1b,
                                                     const float* __restrict__ b1,
                                                     const float* __restrict__ cntf,
                                                     bf16_t* __restrict__ y2b,
                                                     bf16_t* __restrict__ qb,
                                                     bf16_t* __restrict__ kb,
                                                     bf16_t* __restrict__ vtb) {
  const int bid = blockIdx.x;
  const int xcd = bid & 7, j = bid >> 3;      // j in 0..335
  const int mt = xcd * 8 + (j & 7);           // 0..63 (fast within XCD)
  const int nt = j >> 3;                      // 0..41 (slow)
  const int tid = threadIdx.x;
  const int w = tid >> 6, l = tid & 63;
  const int lq = l >> 4, lr = l & 15;

  __shared__ __align__(16) bf16_t lA[128 * 64];
  __shared__ __align__(16) bf16_t lB[128 * 64];

  f32x4 acc[4][4] = {};
  const int mwave = (w & 1) * 64, nwave = (w >> 1) * 64;
  const int crow = l >> 3;
  const int cbg = (l & 7) ^ (crow & 7);

  for (int k0 = 0; k0 < DIM; k0 += 64) {
#pragma unroll
    for (int i = 0; i < 4; i++) {
      int c = w * 4 + i;
      int row = c * 8 + crow;
      async_copy16(ytil + (size_t)(mt * 128 + row) * DIM + k0 + cbg * 8, lA + c * 512);
      async_copy16(w1b + (size_t)(nt * 128 + row) * DIM + k0 + cbg * 8, lB + c * 512);
    }
    __syncthreads();
#pragma unroll
    for (int ks = 0; ks < 2; ks++) {
      const int cbA = ((ks * 4 + lq) ^ (lr & 7)) * 8;
      bf16x8 af[4], bfr[4];
#pragma unroll
      for (int mi = 0; mi < 4; mi++)
        af[mi] = *(const bf16x8*)(lA + (mwave + mi * 16 + lr) * 64 + cbA);
#pragma unroll
      for (int ni = 0; ni < 4; ni++)
        bfr[ni] = *(const bf16x8*)(lB + (nwave + ni * 16 + lr) * 64 + cbA);
#pragma unroll
      for (int mi = 0; mi < 4; mi++)
#pragma unroll
        for (int ni = 0; ni < 4; ni++)
          acc[mi][ni] = __builtin_amdgcn_mfma_f32_16x16x32_bf16(af[mi], bfr[ni], acc[mi][ni], 0, 0, 0);
    }
    __syncthreads();
  }

#pragma unroll
  for (int mi = 0; mi < 4; mi++) {
    int row0 = mt * 128 + mwave + mi * 16 + lq * 4;
    float cnt[4];
#pragma unroll
    for (int r = 0; r < 4; r++) cnt[r] = cntf[row0 + r];
#pragma unroll
    for (int ni = 0; ni < 4; ni++) {
      int col = nt * 128 + nwave + ni * 16 + lr;
      float bias = b1[col];
      if (col < MLP_HID) {
#pragma unroll
        for (int r = 0; r < 4; r++) {
          float v = acc[mi][ni][r] + cnt[r] * bias;
          y2b[(size_t)(row0 + r) * FC2_IN + col] = (bf16_t)gelu_f(v);
        }
      } else {
        int part = col - MLP_HID;
        int comp = (part >= 1536) ? 2 : (part >= 768) ? 1 : 0;
        int rem = part - comp * 768;
        int hh = rem >> 6, d = rem & 63;
        int b = row0 >> 10, n0 = row0 & 1023;
        size_t base = (size_t)(b * NH + hh);
        if (comp == 2) {
          bf16x4 pk;
#pragma unroll
          for (int r = 0; r < 4; r++)
            pk[r] = (bf16_t)(acc[mi][ni][r] + cnt[r] * bias);
          *(bf16x4*)(vtb + (base * HD + d) * 1024 + n0) = pk;
        } else {
#pragma unroll
          for (int r = 0; r < 4; r++) {
            float v = acc[mi][ni][r] + cnt[r] * bias;
            if (comp == 0) qb[(base * 1024 + n0 + r) * HD + d] = (bf16_t)(v * (0.125f * LOG2E));
            else           kb[(base * 1024 + n0 + r) * HD + d] = (bf16_t)v;
          }
        }
      }
    }
  }
}

// ---------------- flash attention, no-max softmax, 128-row Q tiles, XCD-local K/V ----------------
__global__ __launch_bounds__(256) void attn_kernel(const bf16_t* __restrict__ qb,
                                                   const bf16_t* __restrict__ kb,
                                                   const bf16_t* __restrict__ vtb,
                                                   bf16_t* __restrict__ y2b) {
  const int bid = blockIdx.x;                 // 0..767
  const int xcd = bid & 7, j = bid >> 3;      // j 0..95
  const int bh = xcd * 12 + (j >> 3);         // all 8 q-blocks of a head on one XCD
  const int qt = j & 7;                       // 128-row q tile
  const int tid = threadIdx.x;
  const int w = tid >> 6, l = tid & 63, lq = l >> 4, lr = l & 15;

  __shared__ __align__(16) bf16_t lK[64 * 64];
  __shared__ __align__(16) bf16_t lV[64 * 64];
  __shared__ __align__(16) bf16_t lP[4][16 * 72];

  const bf16_t* qbase = qb + (size_t)bh * 1024 * HD;
  const bf16_t* kbase = kb + (size_t)bh * 1024 * HD;
  const bf16_t* vbase = vtb + (size_t)bh * HD * 1024;

  bf16x8 qf[2][2];
#pragma unroll
  for (int h = 0; h < 2; h++) {
    int qrow = qt * 128 + h * 64 + w * 16 + lr;
#pragma unroll
    for (int s = 0; s < 2; s++)
      qf[h][s] = *(const bf16x8*)(qbase + (size_t)qrow * HD + s * 32 + lq * 8);
  }

  f32x4 oacc[2][4] = {};
  float psum[2][4] = {};

  const int crow = l >> 3;
  const int cbg = (l & 7) ^ (crow & 7);

  for (int kt = 0; kt < 16; kt++) {
#pragma unroll
    for (int i = 0; i < 2; i++) {
      int c = w * 2 + i;
      int row = c * 8 + crow;
      async_copy16(kbase + (size_t)(kt * 64 + row) * HD + cbg * 8, lK + c * 512);
      async_copy16(vbase + (size_t)row * 1024 + kt * 64 + cbg * 8, lV + c * 512);
    }
    __syncthreads();

#pragma unroll
    for (int h = 0; h < 2; h++) {
      f32x4 sacc[4] = {};
#pragma unroll
      for (int s = 0; s < 2; s++) {
        const int cb = ((s * 4 + lq) ^ (lr & 7)) * 8;
#pragma unroll
        for (int kbq = 0; kbq < 4; kbq++) {
          bf16x8 kf = *(const bf16x8*)(lK + (kbq * 16 + lr) * 64 + cb);
          sacc[kbq] = __builtin_amdgcn_mfma_f32_16x16x32_bf16(qf[h][s], kf, sacc[kbq], 0, 0, 0);
        }
      }

      // pv = exp2(score); per-lane partial row sums; wave-private lP slab (reused per half)
#pragma unroll
      for (int kbq = 0; kbq < 4; kbq++)
#pragma unroll
        for (int r = 0; r < 4; r++) {
          float pv = exp2f(sacc[kbq][r]);
          psum[h][r] += pv;
          lP[w][(lq * 4 + r) * 72 + kbq * 16 + lr] = (bf16_t)pv;
        }

      bf16x8 pf[2];
#pragma unroll
      for (int s = 0; s < 2; s++)
        pf[s] = *(const bf16x8*)(&lP[w][lr * 72 + s * 32 + lq * 8]);

#pragma unroll
      for (int s = 0; s < 2; s++) {
        const int cb = ((s * 4 + lq) ^ (lr & 7)) * 8;
#pragma unroll
        for (int nb = 0; nb < 4; nb++) {
          bf16x8 vf = *(const bf16x8*)(lV + (nb * 16 + lr) * 64 + cb);
          oacc[h][nb] = __builtin_amdgcn_mfma_f32_16x16x32_bf16(pf[s], vf, oacc[h][nb], 0, 0, 0);
        }
      }
    }
    __syncthreads();
  }

  int b = bh / NH, hh = bh % NH;
#pragma unroll
  for (int h = 0; h < 2; h++) {
#pragma unroll
    for (int off = 1; off < 16; off <<= 1)
#pragma unroll
      for (int r = 0; r < 4; r++) psum[h][r] += __shfl_xor(psum[h][r], off);
    float rinv[4];
#pragma unroll
    for (int r = 0; r < 4; r++) rinv[r] = 1.0f / psum[h][r];
#pragma unroll
    for (int nb = 0; nb < 4; nb++)
#pragma unroll
      for (int r = 0; r < 4; r++) {
        float v = oacc[h][nb][r] * rinv[r];
        int tok = qt * 128 + h * 64 + w * 16 + lq * 4 + r;
        y2b[((size_t)(b * 1024 + tok)) * FC2_IN + MLP_HID + hh * HD + nb * 16 + lr] = (bf16_t)v;
      }
  }
}

// ---------------- FC2 dense fused: out = x + Sum_halves G_seg(col) * (y2 @ w2^T + b2) ----------------
__global__ __launch_bounds__(256, 4) void fc2_kernel(const bf16_t* __restrict__ y2b,
                                                     const bf16_t* __restrict__ w2b,
                                                     const float* __restrict__ b2,
                                                     const float* __restrict__ g4,
                                                     const float* __restrict__ x,
                                                     float* __restrict__ out) {
  const int bid = blockIdx.x;
  const int xcd = bid & 7, j = bid >> 3;
  const int mt = xcd * 8 + j / 12;
  const int ct = j % 12;
  const int tid = threadIdx.x;
  const int w = tid >> 6, l = tid & 63;
  const int lq = l >> 4, lr = l & 15;

  __shared__ __align__(16) bf16_t lA[128 * 64];
  __shared__ __align__(16) bf16_t lB[128 * 64];

  f32x4 acc[2][4][2] = {};
  const int mwave = (w & 1) * 64, nwave = (w >> 1) * 32;
  const int crow = l >> 3;
  const int cbg = (l & 7) ^ (crow & 7);

  for (int k0 = 0; k0 < FC2_IN; k0 += 64) {
#pragma unroll
    for (int i = 0; i < 4; i++) {
      int c = w * 4 + i;
      int row = c * 8 + crow;
      async_copy16(y2b + (size_t)(mt * 128 + row) * FC2_IN + k0 + cbg * 8, lA + c * 512);
      int grow = ((row >> 6) * 768) + ct * 64 + (row & 63);
      async_copy16(w2b + (size_t)grow * FC2_IN + k0 + cbg * 8, lB + c * 512);
    }
    __syncthreads();
#pragma unroll
    for (int ks = 0; ks < 2; ks++) {
      const int cbA = ((ks * 4 + lq) ^ (lr & 7)) * 8;
      bf16x8 af[4], bfr[2][2];
#pragma unroll
      for (int mi = 0; mi < 4; mi++)
        af[mi] = *(const bf16x8*)(lA + (mwave + mi * 16 + lr) * 64 + cbA);
#pragma unroll
      for (int h = 0; h < 2; h++)
#pragma unroll
        for (int ni = 0; ni < 2; ni++)
          bfr[h][ni] = *(const bf16x8*)(lB + (h * 64 + nwave + ni * 16 + lr) * 64 + cbA);
#pragma unroll
      for (int h = 0; h < 2; h++)
#pragma unroll
        for (int mi = 0; mi < 4; mi++)
#pragma unroll
          for (int ni = 0; ni < 2; ni++)
            acc[h][mi][ni] = __builtin_amdgcn_mfma_f32_16x16x32_bf16(af[mi], bfr[h][ni], acc[h][mi][ni], 0, 0, 0);
    }
    __syncthreads();
  }

#pragma unroll
  for (int mi = 0; mi < 4; mi++) {
    int row0 = mt * 128 + mwave + mi * 16 + lq * 4;
    float4 G[4];
#pragma unroll
    for (int r = 0; r < 4; r++) G[r] = ((const float4*)g4)[row0 + r];
#pragma unroll
    for (int ni = 0; ni < 2; ni++) {
      int col = ct * 64 + nwave + ni * 16 + lr;
      float b20 = b2[col], b21 = b2[768 + col];
#pragma unroll
      for (int r = 0; r < 4; r++) {
        float gw = (col < 96) ? G[r].x : (col < 192) ? G[r].y : (col < 384) ? G[r].z : G[r].w;
        float o = (acc[0][mi][ni][r] + b20) + (acc[1][mi][ni][r] + b21);
        size_t idx = (size_t)(row0 + r) * DIM + col;
        out[idx] = x[idx] + gw * o;
      }
    }
  }
}

extern "C" void kernel_launch(void* const* d_in, const int* in_sizes, int n_in,
                              void* d_out, int out_size, void* d_ws, size_t ws_size,
                              hipStream_t stream) {
  const float* x     = (const float*)d_in[0];
  const float* wr    = (const float*)d_in[1];
  const float* gamma = (const float*)d_in[2];
  const float* beta  = (const float*)d_in[3];
  const float* w1    = (const float*)d_in[4];
  const float* b1    = (const float*)d_in[5];
  const float* w2    = (const float*)d_in[6];
  const float* b2    = (const float*)d_in[7];
  float* out = (float*)d_out;

  char* ws = (char*)d_ws;
  float*  probs    = (float*)(ws + 0);            // 131072
  float*  gate_tok = (float*)(ws + 131072);       // 131072
  float*  cntf     = (float*)(ws + 262144);       // 32768
  float*  g4       = (float*)(ws + 294912);       // 131072
  bf16_t* w1b      = (bf16_t*)(ws + 425984);      // 8257536
  bf16_t* w2b      = (bf16_t*)(ws + 8683520);     // 11796480
  bf16_t* ytil     = (bf16_t*)(ws + 20480000);    // 12582912
  bf16_t* y2b      = (bf16_t*)(ws + 33062912);    // 62914560
  bf16_t* qb       = (bf16_t*)(ws + 95977472);    // 12582912
  bf16_t* kb       = (bf16_t*)(ws + 108560384);   // 12582912
  bf16_t* vtb      = (bf16_t*)(ws + 121143296);   // 12582912

  cast_router_kernel<<<4096, 256, 0, stream>>>(w1, w2, w1b, w2b, x, wr, probs);
  rank_kernel<<<dim3(4, 32), 256, 0, stream>>>(probs, gate_tok);
  ln_kernel<<<2048, 256, 0, stream>>>(x, gamma, beta, gate_tok, ytil, cntf, g4);
  fc1_kernel<<<2688, 256, 0, stream>>>(ytil, w1b, b1, cntf, y2b, qb, kb, vtb);
  attn_kernel<<<768, 256, 0, stream>>>(qb, kb, vtb, y2b);
  fc2_kernel<<<768, 256, 0, stream>>>(y2b, w2b, b2, g4, x, out);
}